// Round 1
// baseline (1705.089 us; speedup 1.0000x reference)
//
#include <hip/hip_runtime.h>
#include <hip/hip_bf16.h>
#include <math.h>

#define NPIX   262144          // 512*512
#define NP     4194304         // 16*512*512
#define NBINS  8192
#define SIG    0.125f
#define TAUC   0.125f
#define ALPHAC 0.15f
#define MUC    10.0f
#define EPSC   1e-6f

// ---------------- horizontal 31-max over rows ----------------
__global__ __launch_bounds__(512) void hpass_k(const float* __restrict__ in,
                                               float* __restrict__ out) {
    int y  = blockIdx.x;        // 0..511
    int bc = blockIdx.y;        // 0..47 (b*3+c)
    int tid = threadIdx.x;      // 0..511
    __shared__ float row[512];
    size_t ibase = (size_t)bc * NPIX + (size_t)y * 512;
    row[tid] = in[ibase + tid];
    __syncthreads();
    int lo = max(tid - 15, 0), hi = min(tid + 15, 511);
    float m = -3.4e38f;
    for (int i = lo; i <= hi; ++i) m = fmaxf(m, row[i]);
    int b = bc / 3, c = bc % 3;
    out[((size_t)c * 16 + b) * NPIX + (size_t)y * 512 + tid] = m;
}

// ---------------- vertical 31-max + |Rmax - GBmax| + R ----------------
__global__ __launch_bounds__(256) void vpass_k(const float* __restrict__ H,
                                               const float* __restrict__ Iy,
                                               float* __restrict__ xb) {
    int x = blockIdx.x * 64 + threadIdx.x;
    int y = blockIdx.y * 4  + threadIdx.y;
    int b = blockIdx.z;
    const float* HR = H + (size_t)(0 * 16 + b) * NPIX;
    const float* HG = H + (size_t)(1 * 16 + b) * NPIX;
    const float* HB = H + (size_t)(2 * 16 + b) * NPIX;
    int y0 = max(y - 15, 0), y1 = min(y + 15, 511);
    float mr = -3.4e38f, mg = -3.4e38f, mb = -3.4e38f;
    for (int yy = y0; yy <= y1; ++yy) {
        int o = yy * 512 + x;
        mr = fmaxf(mr, HR[o]);
        mg = fmaxf(mg, HG[o]);
        mb = fmaxf(mb, HB[o]);
    }
    float R = Iy[(size_t)(b * 3) * NPIX + (size_t)y * 512 + x];
    xb[(size_t)b * NPIX + (size_t)y * 512 + x] = fabsf(mr - fmaxf(mg, mb)) + R;
}

// ---------------- per-batch histogram over [0,2) ----------------
__global__ __launch_bounds__(1024) void hist_k(const float* __restrict__ v,
                                               int* __restrict__ hist) {
    __shared__ int lh[NBINS];
    int b = blockIdx.x, tid = threadIdx.x;
    for (int i = tid; i < NBINS; i += 1024) lh[i] = 0;
    __syncthreads();
    const float* p = v + (size_t)b * NPIX;
    for (int i = tid; i < NPIX; i += 1024) {
        int bin = (int)(p[i] * (NBINS * 0.5f));
        bin = min(max(bin, 0), NBINS - 1);
        atomicAdd(&lh[bin], 1);
    }
    __syncthreads();
    for (int i = tid; i < NBINS; i += 1024) hist[b * NBINS + i] = lh[i];
}

// histogram of gradient magnitude of N_hat (computed on the fly)
__global__ __launch_bounds__(1024) void gradhist_k(const float* __restrict__ nh,
                                                   int* __restrict__ hist) {
    __shared__ int lh[NBINS];
    int b = blockIdx.x, tid = threadIdx.x;
    for (int i = tid; i < NBINS; i += 1024) lh[i] = 0;
    __syncthreads();
    const float* p = nh + (size_t)b * NPIX;
    for (int i = tid; i < NPIX; i += 1024) {
        float c = p[i];
        int x = i & 511, y = i >> 9;
        float dx = (x < 511) ? p[i + 1]   - c : 0.f;
        float dy = (y < 511) ? p[i + 512] - c : 0.f;
        float gm = sqrtf(dx * dx + dy * dy + EPSC);
        int bin = (int)(gm * (NBINS * 0.5f));
        bin = min(max(bin, 0), NBINS - 1);
        atomicAdd(&lh[bin], 1);
    }
    __syncthreads();
    for (int i = tid; i < NBINS; i += 1024) hist[b * NBINS + i] = lh[i];
}

// ---------------- quantile from histogram (linear within-bin) ----------------
__global__ __launch_bounds__(1024) void quant_k(const int* __restrict__ hist,
                                                float* __restrict__ scal,
                                                float q0, float q1, int s0, int s1) {
    __shared__ int csum[1025];
    int b = blockIdx.x, tid = threadIdx.x;
    const int* h = hist + b * NBINS;
    int s = 0;
#pragma unroll
    for (int j = 0; j < NBINS / 1024; ++j) s += h[tid * (NBINS / 1024) + j];
    csum[tid] = s;
    __syncthreads();
    if (tid == 0) {
        int acc = 0;
        for (int i = 0; i < 1024; ++i) { int v = csum[i]; csum[i] = acc; acc += v; }
        csum[1024] = acc;
    }
    __syncthreads();
    if (tid < 2) {
        int slot = tid ? s1 : s0;
        if (slot >= 0) {
            float q = tid ? q1 : q0;
            float t = q * (float)(NPIX - 1);
            int chunk = 1023;
            for (int i = 0; i < 1024; ++i) {
                if ((float)csum[i + 1] > t) { chunk = i; break; }
            }
            int per = NBINS / 1024;
            int cb = csum[chunk];
            int bin = chunk * per;
            int hv = 1;
            for (int j = 0; j < per; ++j) {
                hv = h[chunk * per + j];
                if ((float)(cb + hv) > t) { bin = chunk * per + j; break; }
                cb += hv;
            }
            float k = t - (float)cb;
            float val = ((float)bin + (k + 0.5f) / (float)hv) * (2.0f / NBINS);
            scal[b * 4 + slot] = val;
        }
    }
}

// ---------------- N_hat = clip((x-lo)/(hi-lo+eps),0,1)  (in place) ----------------
__global__ __launch_bounds__(256) void nhat_k(float* __restrict__ xb,
                                              const float* __restrict__ scal) {
    size_t i = (size_t)blockIdx.x * 256 + threadIdx.x;
    if (i >= NP) return;
    int b = (int)(i >> 18);
    float lo = scal[b * 4 + 0], hi = scal[b * 4 + 1];
    float v = (xb[i] - lo) / (hi - lo + EPSC);
    xb[i] = fminf(fmaxf(v, 0.f), 1.f);
}

// ---------------- bounds bx/by = ALPHA*W, zero-init px/py ----------------
__global__ __launch_bounds__(256) void w_k(const float* __restrict__ nh,
                                           const float* __restrict__ scal,
                                           float* __restrict__ bx, float* __restrict__ by,
                                           float* __restrict__ px, float* __restrict__ py) {
    int x = blockIdx.x * 64 + threadIdx.x;
    int y = blockIdx.y * 4  + threadIdx.y;
    int b = blockIdx.z;
    size_t base = (size_t)b * NPIX + (size_t)y * 512 + x;
    float c = nh[base];
    float dx = (x < 511) ? nh[base + 1]   - c : 0.f;
    float dy = (y < 511) ? nh[base + 512] - c : 0.f;
    float sgm = fmaxf(scal[b * 4 + 2], EPSC);
    float inv = 1.0f / sgm;
    bx[base] = ALPHAC * (1.f + MUC * expf(-fabsf(dx) * inv));
    by[base] = ALPHAC * (1.f + MUC * expf(-fabsf(dy) * inv));
    px[base] = 0.f;
    py[base] = 0.f;
}

// ---------------- PD step 1: px/py update (in place, no cross-thread deps) ----------------
__global__ __launch_bounds__(256) void pd1_k(const float* __restrict__ u,
                                             const float* __restrict__ up,
                                             float* __restrict__ px, float* __restrict__ py,
                                             const float* __restrict__ bx,
                                             const float* __restrict__ by) {
    int x = blockIdx.x * 64 + threadIdx.x;
    int y = blockIdx.y * 4  + threadIdx.y;
    int b = blockIdx.z;
    size_t base = (size_t)b * NPIX + (size_t)y * 512 + x;
    float ubc = 2.f * u[base] - up[base];
    float dx = 0.f, dy = 0.f;
    if (x < 511) { float r = 2.f * u[base + 1]   - up[base + 1];   dx = r - ubc; }
    if (y < 511) { float d = 2.f * u[base + 512] - up[base + 512]; dy = d - ubc; }
    float bxv = bx[base], byv = by[base];
    float pxv = px[base] + SIG * dx;
    float pyv = py[base] + SIG * dy;
    px[base] = fminf(fmaxf(pxv, -bxv), bxv);
    py[base] = fminf(fmaxf(pyv, -byv), byv);
}

// ---------------- PD step 2: divergence + u update ----------------
__global__ __launch_bounds__(256) void pd2_k(const float* __restrict__ u,
                                             const float* __restrict__ px,
                                             const float* __restrict__ py,
                                             const float* __restrict__ nh,
                                             float* __restrict__ un) {
    int x = blockIdx.x * 64 + threadIdx.x;
    int y = blockIdx.y * 4  + threadIdx.y;
    int b = blockIdx.z;
    size_t base = (size_t)b * NPIX + (size_t)y * 512 + x;
    float div = px[base] + py[base];
    if (x > 0) div -= px[base - 1];
    if (y > 0) div -= py[base - 512];
    float v = u[base] + TAUC * div;
    un[base] = (v + TAUC * nh[base]) * (1.0f / (1.0f + TAUC));
}

// ---------------- final clip ----------------
__global__ __launch_bounds__(256) void clip_k(const float* __restrict__ u,
                                              float* __restrict__ out) {
    size_t i = (size_t)blockIdx.x * 256 + threadIdx.x;
    if (i >= NP) return;
    out[i] = fminf(fmaxf(u[i], 0.f), 1.f);
}

extern "C" void kernel_launch(void* const* d_in, const int* in_sizes, int n_in,
                              void* d_out, int out_size, void* d_ws, size_t ws_size,
                              hipStream_t stream) {
    const float* Iy = (const float*)d_in[0];
    float* ws = (float*)d_ws;

    float* H   = ws;                 // 3*NP: Rh/Gh/Bh, later reused as bx/by/px
    float* xb  = ws + (size_t)3 * NP;  // x -> N_hat (in place)
    float* py  = ws + (size_t)4 * NP;
    float* U0  = ws + (size_t)5 * NP;
    float* U1  = ws + (size_t)6 * NP;
    float* U2  = ws + (size_t)7 * NP;
    int*   hist = (int*)(ws + (size_t)8 * NP);           // 16*NBINS ints
    float* scal = ws + (size_t)8 * NP + 16 * NBINS;      // 16*4 floats

    float* bx = H;
    float* by = H + (size_t)NP;
    float* px = H + (size_t)2 * NP;

    dim3 tile_b(64, 4), tile_g(8, 128, 16);

    // 1. separable 31x31 max pool + Dmip
    hpass_k<<<dim3(512, 48), dim3(512), 0, stream>>>(Iy, H);
    vpass_k<<<tile_g, tile_b, 0, stream>>>(H, Iy, xb);

    // 2. robust normalize (1%/99% quantiles)
    hist_k<<<16, 1024, 0, stream>>>(xb, hist);
    quant_k<<<16, 1024, 0, stream>>>(hist, scal, 0.01f, 0.99f, 0, 1);
    nhat_k<<<(NP + 255) / 256, 256, 0, stream>>>(xb, scal);

    // 3. median of gradient magnitude -> sigma -> bounds; zero px/py
    gradhist_k<<<16, 1024, 0, stream>>>(xb, hist);
    quant_k<<<16, 1024, 0, stream>>>(hist, scal, 0.5f, 0.5f, 2, -1);
    w_k<<<tile_g, tile_b, 0, stream>>>(xb, scal, bx, by, px, py);

    // 4. 30 primal-dual iterations; u_bar = 2u - u_prev (theta=1)
    const float* ucur = xb;   // u0 = N_hat
    const float* uprev = xb;  // so that 2u0 - uprev = N_hat
    float* Ubuf[3] = {U0, U1, U2};
    for (int t = 0; t < 30; ++t) {
        float* un = Ubuf[t % 3];
        pd1_k<<<tile_g, tile_b, 0, stream>>>(ucur, uprev, px, py, bx, by);
        pd2_k<<<tile_g, tile_b, 0, stream>>>(ucur, px, py, xb, un);
        uprev = ucur;
        ucur = un;
    }

    // 5. clip to [0,1]
    clip_k<<<(NP + 255) / 256, 256, 0, stream>>>(ucur, (float*)d_out);
}

// Round 2
// 1153.509 us; speedup vs baseline: 1.4782x; 1.4782x over previous
//
#include <hip/hip_runtime.h>
#include <hip/hip_bf16.h>
#include <math.h>

#define NPIX   262144          // 512*512
#define NP     4194304         // 16*512*512
#define NBINS  8192
#define HSUB   16              // histogram sub-blocks per batch
#define SIG    0.125f
#define TAUC   0.125f
#define ALPHAC 0.15f
#define MUC    10.0f
#define EPSC   1e-6f

// ---------------- horizontal 31-max over rows ----------------
__global__ __launch_bounds__(512) void hpass_k(const float* __restrict__ in,
                                               float* __restrict__ out) {
    int y  = blockIdx.x;        // 0..511
    int bc = blockIdx.y;        // 0..47 (b*3+c)
    int tid = threadIdx.x;      // 0..511
    __shared__ float row[512];
    size_t ibase = (size_t)bc * NPIX + (size_t)y * 512;
    row[tid] = in[ibase + tid];
    __syncthreads();
    int lo = max(tid - 15, 0), hi = min(tid + 15, 511);
    float m = -3.4e38f;
    for (int i = lo; i <= hi; ++i) m = fmaxf(m, row[i]);
    int b = bc / 3, c = bc % 3;
    out[((size_t)c * 16 + b) * NPIX + (size_t)y * 512 + tid] = m;
}

// ---------------- vertical 31-max + |Rmax - GBmax| + R ----------------
__global__ __launch_bounds__(256) void vpass_k(const float* __restrict__ H,
                                               const float* __restrict__ Iy,
                                               float* __restrict__ xb) {
    int x = blockIdx.x * 64 + threadIdx.x;
    int y = blockIdx.y * 4  + threadIdx.y;
    int b = blockIdx.z;
    const float* HR = H + (size_t)(0 * 16 + b) * NPIX;
    const float* HG = H + (size_t)(1 * 16 + b) * NPIX;
    const float* HB = H + (size_t)(2 * 16 + b) * NPIX;
    int y0 = max(y - 15, 0), y1 = min(y + 15, 511);
    float mr = -3.4e38f, mg = -3.4e38f, mb = -3.4e38f;
    for (int yy = y0; yy <= y1; ++yy) {
        int o = yy * 512 + x;
        mr = fmaxf(mr, HR[o]);
        mg = fmaxf(mg, HG[o]);
        mb = fmaxf(mb, HB[o]);
    }
    float R = Iy[(size_t)(b * 3) * NPIX + (size_t)y * 512 + x];
    xb[(size_t)b * NPIX + (size_t)y * 512 + x] = fabsf(mr - fmaxf(mg, mb)) + R;
}

// ---------------- zero int buffer ----------------
__global__ __launch_bounds__(1024) void zeroi_k(int* __restrict__ p) {
    p[blockIdx.x * 1024 + threadIdx.x] = 0;
}

// ---------------- per-batch histogram over [0,2), HSUB blocks/batch ----------------
__global__ __launch_bounds__(1024) void hist2_k(const float* __restrict__ v,
                                                int* __restrict__ hist) {
    __shared__ int lh[NBINS];
    int s = blockIdx.x, b = blockIdx.y, tid = threadIdx.x;
    for (int i = tid; i < NBINS; i += 1024) lh[i] = 0;
    __syncthreads();
    const float* p = v + (size_t)b * NPIX + (size_t)s * (NPIX / HSUB);
    for (int i = tid; i < NPIX / HSUB; i += 1024) {
        int bin = (int)(p[i] * (NBINS * 0.5f));
        bin = min(max(bin, 0), NBINS - 1);
        atomicAdd(&lh[bin], 1);
    }
    __syncthreads();
    for (int i = tid; i < NBINS; i += 1024) {
        int c = lh[i];
        if (c) atomicAdd(&hist[b * NBINS + i], c);
    }
}

// histogram of gradient magnitude of N_hat (computed on the fly)
__global__ __launch_bounds__(1024) void gradhist2_k(const float* __restrict__ nh,
                                                    int* __restrict__ hist) {
    __shared__ int lh[NBINS];
    int s = blockIdx.x, b = blockIdx.y, tid = threadIdx.x;
    for (int i = tid; i < NBINS; i += 1024) lh[i] = 0;
    __syncthreads();
    const float* p = nh + (size_t)b * NPIX;
    int base = s * (NPIX / HSUB);
    for (int ii = tid; ii < NPIX / HSUB; ii += 1024) {
        int i = base + ii;
        float c = p[i];
        int x = i & 511, y = i >> 9;
        float dx = (x < 511) ? p[i + 1]   - c : 0.f;
        float dy = (y < 511) ? p[i + 512] - c : 0.f;
        float gm = sqrtf(dx * dx + dy * dy + EPSC);
        int bin = (int)(gm * (NBINS * 0.5f));
        bin = min(max(bin, 0), NBINS - 1);
        atomicAdd(&lh[bin], 1);
    }
    __syncthreads();
    for (int i = tid; i < NBINS; i += 1024) {
        int c = lh[i];
        if (c) atomicAdd(&hist[b * NBINS + i], c);
    }
}

// ---------------- quantile from histogram (linear within-bin) ----------------
__global__ __launch_bounds__(1024) void quant_k(const int* __restrict__ hist,
                                                float* __restrict__ scal,
                                                float q0, float q1, int s0, int s1) {
    __shared__ int csum[1025];
    int b = blockIdx.x, tid = threadIdx.x;
    const int* h = hist + b * NBINS;
    int s = 0;
#pragma unroll
    for (int j = 0; j < NBINS / 1024; ++j) s += h[tid * (NBINS / 1024) + j];
    csum[tid] = s;
    __syncthreads();
    if (tid == 0) {
        int acc = 0;
        for (int i = 0; i < 1024; ++i) { int v = csum[i]; csum[i] = acc; acc += v; }
        csum[1024] = acc;
    }
    __syncthreads();
    if (tid < 2) {
        int slot = tid ? s1 : s0;
        if (slot >= 0) {
            float q = tid ? q1 : q0;
            float t = q * (float)(NPIX - 1);
            int chunk = 1023;
            for (int i = 0; i < 1024; ++i) {
                if ((float)csum[i + 1] > t) { chunk = i; break; }
            }
            int per = NBINS / 1024;
            int cb = csum[chunk];
            int bin = chunk * per;
            int hv = 1;
            for (int j = 0; j < per; ++j) {
                hv = h[chunk * per + j];
                if ((float)(cb + hv) > t) { bin = chunk * per + j; break; }
                cb += hv;
            }
            float k = t - (float)cb;
            float val = ((float)bin + (k + 0.5f) / (float)hv) * (2.0f / NBINS);
            scal[b * 4 + slot] = val;
        }
    }
}

// ---------------- N_hat = clip((x-lo)/(hi-lo+eps),0,1)  (in place, float4) ----------------
__global__ __launch_bounds__(256) void nhat_k(float* __restrict__ xb,
                                              const float* __restrict__ scal) {
    size_t i = ((size_t)blockIdx.x * 256 + threadIdx.x) * 4;
    int b = (int)(i >> 18);
    float lo = scal[b * 4 + 0], hi = scal[b * 4 + 1];
    float inv = 1.0f / (hi - lo + EPSC);
    float4 v = *(const float4*)(xb + i);
    v.x = fminf(fmaxf((v.x - lo) * inv, 0.f), 1.f);
    v.y = fminf(fmaxf((v.y - lo) * inv, 0.f), 1.f);
    v.z = fminf(fmaxf((v.z - lo) * inv, 0.f), 1.f);
    v.w = fminf(fmaxf((v.w - lo) * inv, 0.f), 1.f);
    *(float4*)(xb + i) = v;
}

// ---------------- bounds bx/by = ALPHA*W, zero-init px/py ----------------
__global__ __launch_bounds__(256) void w_k(const float* __restrict__ nh,
                                           const float* __restrict__ scal,
                                           float* __restrict__ bx, float* __restrict__ by,
                                           float* __restrict__ px, float* __restrict__ py) {
    int x = blockIdx.x * 64 + threadIdx.x;
    int y = blockIdx.y * 4  + threadIdx.y;
    int b = blockIdx.z;
    size_t base = (size_t)b * NPIX + (size_t)y * 512 + x;
    float c = nh[base];
    float dx = (x < 511) ? nh[base + 1]   - c : 0.f;
    float dy = (y < 511) ? nh[base + 512] - c : 0.f;
    float sgm = fmaxf(scal[b * 4 + 2], EPSC);
    float inv = 1.0f / sgm;
    bx[base] = ALPHAC * (1.f + MUC * expf(-fabsf(dx) * inv));
    by[base] = ALPHAC * (1.f + MUC * expf(-fabsf(dy) * inv));
    px[base] = 0.f;
    py[base] = 0.f;
}

// ---------------- fused PD iteration: p-update + divergence + u-update ----------------
// ping-pong px/py; halo p-values recomputed locally (bit-identical arithmetic)
__global__ __launch_bounds__(256) void pdf_k(const float* __restrict__ u,
                                             const float* __restrict__ up,
                                             const float* __restrict__ pxO,
                                             const float* __restrict__ pyO,
                                             float* __restrict__ pxN,
                                             float* __restrict__ pyN,
                                             const float* __restrict__ bxA,
                                             const float* __restrict__ byA,
                                             const float* __restrict__ nh,
                                             float* __restrict__ un,
                                             int last) {
    int x0 = (blockIdx.x * 64 + threadIdx.x) * 4;
    int y  = blockIdx.y * 4 + threadIdx.y;
    int b  = blockIdx.z;
    size_t base = (size_t)b * NPIX + (size_t)y * 512 + x0;
    bool hasD = (y < 511), hasU = (y > 0);

    float uc[4], upc[4], ud[4] = {0}, upd[4] = {0}, uu[4] = {0}, upu[4] = {0};
    { float4 t = *(const float4*)(u  + base); uc[0]=t.x; uc[1]=t.y; uc[2]=t.z; uc[3]=t.w; }
    { float4 t = *(const float4*)(up + base); upc[0]=t.x; upc[1]=t.y; upc[2]=t.z; upc[3]=t.w; }
    if (hasD) {
        float4 t = *(const float4*)(u  + base + 512); ud[0]=t.x; ud[1]=t.y; ud[2]=t.z; ud[3]=t.w;
        float4 s = *(const float4*)(up + base + 512); upd[0]=s.x; upd[1]=s.y; upd[2]=s.z; upd[3]=s.w;
    }
    if (hasU) {
        float4 t = *(const float4*)(u  + base - 512); uu[0]=t.x; uu[1]=t.y; uu[2]=t.z; uu[3]=t.w;
        float4 s = *(const float4*)(up + base - 512); upu[0]=s.x; upu[1]=s.y; upu[2]=s.z; upu[3]=s.w;
    }
    float bl = 0.f, br = 0.f;
    if (x0 > 0)   bl = 2.f * u[base - 1] - up[base - 1];
    if (x0 < 508) br = 2.f * u[base + 4] - up[base + 4];

    float bc[4], bd[4], bu[4];
#pragma unroll
    for (int i = 0; i < 4; ++i) {
        bc[i] = 2.f * uc[i] - upc[i];
        bd[i] = 2.f * ud[i] - upd[i];
        bu[i] = 2.f * uu[i] - upu[i];
    }

    float pxc[4], bxc[4], pyc[4], byc[4], pyu[4] = {0}, byu[4] = {0};
    { float4 t = *(const float4*)(pxO + base); pxc[0]=t.x; pxc[1]=t.y; pxc[2]=t.z; pxc[3]=t.w; }
    { float4 t = *(const float4*)(bxA + base); bxc[0]=t.x; bxc[1]=t.y; bxc[2]=t.z; bxc[3]=t.w; }
    { float4 t = *(const float4*)(pyO + base); pyc[0]=t.x; pyc[1]=t.y; pyc[2]=t.z; pyc[3]=t.w; }
    { float4 t = *(const float4*)(byA + base); byc[0]=t.x; byc[1]=t.y; byc[2]=t.z; byc[3]=t.w; }
    if (hasU) {
        float4 t = *(const float4*)(pyO + base - 512); pyu[0]=t.x; pyu[1]=t.y; pyu[2]=t.z; pyu[3]=t.w;
        float4 s = *(const float4*)(byA + base - 512); byu[0]=s.x; byu[1]=s.y; byu[2]=s.z; byu[3]=s.w;
    }

    float pxm1 = 0.f;
    if (x0 > 0) {
        float pxl = pxO[base - 1], bxl = bxA[base - 1];
        float dxm1 = bc[0] - bl;
        pxm1 = fminf(fmaxf(pxl + SIG * dxm1, -bxl), bxl);
    }

    float pxn[4], pyn[4], pynU[4];
#pragma unroll
    for (int i = 0; i < 4; ++i) {
        float right = (i < 3) ? bc[i + 1] : br;
        float dx = (x0 + i < 511) ? right - bc[i] : 0.f;
        pxn[i] = fminf(fmaxf(pxc[i] + SIG * dx, -bxc[i]), bxc[i]);
        float dy = hasD ? bd[i] - bc[i] : 0.f;
        pyn[i] = fminf(fmaxf(pyc[i] + SIG * dy, -byc[i]), byc[i]);
        float dyU = bc[i] - bu[i];
        pynU[i] = fminf(fmaxf(pyu[i] + SIG * dyU, -byu[i]), byu[i]);
    }

    *(float4*)(pxN + base) = make_float4(pxn[0], pxn[1], pxn[2], pxn[3]);
    *(float4*)(pyN + base) = make_float4(pyn[0], pyn[1], pyn[2], pyn[3]);

    float nhc[4];
    { float4 t = *(const float4*)(nh + base); nhc[0]=t.x; nhc[1]=t.y; nhc[2]=t.z; nhc[3]=t.w; }
    float unew[4];
#pragma unroll
    for (int i = 0; i < 4; ++i) {
        float left = (i > 0) ? pxn[i - 1] : pxm1;          // pxm1 == 0 when x0 == 0
        float div = pxn[i] + pyn[i] - left - (hasU ? pynU[i] : 0.f);
        float v = (uc[i] + TAUC * div + TAUC * nhc[i]) * (1.0f / (1.0f + TAUC));
        if (last) v = fminf(fmaxf(v, 0.f), 1.f);
        unew[i] = v;
    }
    *(float4*)(un + base) = make_float4(unew[0], unew[1], unew[2], unew[3]);
}

// ---------------- fallback (non-fused) PD kernels ----------------
__global__ __launch_bounds__(256) void pd1_k(const float* __restrict__ u,
                                             const float* __restrict__ up,
                                             float* __restrict__ px, float* __restrict__ py,
                                             const float* __restrict__ bx,
                                             const float* __restrict__ by) {
    int x = blockIdx.x * 64 + threadIdx.x;
    int y = blockIdx.y * 4  + threadIdx.y;
    int b = blockIdx.z;
    size_t base = (size_t)b * NPIX + (size_t)y * 512 + x;
    float ubc = 2.f * u[base] - up[base];
    float dx = 0.f, dy = 0.f;
    if (x < 511) { float r = 2.f * u[base + 1]   - up[base + 1];   dx = r - ubc; }
    if (y < 511) { float d = 2.f * u[base + 512] - up[base + 512]; dy = d - ubc; }
    float bxv = bx[base], byv = by[base];
    float pxv = px[base] + SIG * dx;
    float pyv = py[base] + SIG * dy;
    px[base] = fminf(fmaxf(pxv, -bxv), bxv);
    py[base] = fminf(fmaxf(pyv, -byv), byv);
}

__global__ __launch_bounds__(256) void pd2_k(const float* __restrict__ u,
                                             const float* __restrict__ px,
                                             const float* __restrict__ py,
                                             const float* __restrict__ nh,
                                             float* __restrict__ un) {
    int x = blockIdx.x * 64 + threadIdx.x;
    int y = blockIdx.y * 4  + threadIdx.y;
    int b = blockIdx.z;
    size_t base = (size_t)b * NPIX + (size_t)y * 512 + x;
    float div = px[base] + py[base];
    if (x > 0) div -= px[base - 1];
    if (y > 0) div -= py[base - 512];
    float v = u[base] + TAUC * div;
    un[base] = (v + TAUC * nh[base]) * (1.0f / (1.0f + TAUC));
}

__global__ __launch_bounds__(256) void clip_k(const float* __restrict__ u,
                                              float* __restrict__ out) {
    size_t i = ((size_t)blockIdx.x * 256 + threadIdx.x) * 4;
    float4 v = *(const float4*)(u + i);
    v.x = fminf(fmaxf(v.x, 0.f), 1.f);
    v.y = fminf(fmaxf(v.y, 0.f), 1.f);
    v.z = fminf(fmaxf(v.z, 0.f), 1.f);
    v.w = fminf(fmaxf(v.w, 0.f), 1.f);
    *(float4*)(out + i) = v;
}

extern "C" void kernel_launch(void* const* d_in, const int* in_sizes, int n_in,
                              void* d_out, int out_size, void* d_ws, size_t ws_size,
                              hipStream_t stream) {
    const float* Iy = (const float*)d_in[0];
    float* ws = (float*)d_ws;
    float* out = (float*)d_out;

    dim3 tile_b(64, 4), tile_g(8, 128, 16);   // scalar kernels
    dim3 f4_g(2, 128, 16);                    // float4 kernels
    dim3 hist_g(HSUB, 16);

    size_t need_fused = (size_t)9 * NP * 4 + (size_t)16 * NBINS * 4 + 256;

    if (ws_size >= need_fused) {
        // fused layout: bx,by,pxA | nh | pyA | pxB | pyB | U0 | U1 | hist | scal
        float* bx  = ws;
        float* by  = ws + (size_t)NP;
        float* pxA = ws + (size_t)2 * NP;
        float* xb  = ws + (size_t)3 * NP;     // nh
        float* pyA = ws + (size_t)4 * NP;
        float* pxB = ws + (size_t)5 * NP;
        float* pyB = ws + (size_t)6 * NP;
        float* U0  = ws + (size_t)7 * NP;
        float* U1  = ws + (size_t)8 * NP;
        int*   hist = (int*)(ws + (size_t)9 * NP);
        float* scal = ws + (size_t)9 * NP + 16 * NBINS;
        float* H = ws;   // hpass output reuses bx,by,pxA region (3*NP)

        hpass_k<<<dim3(512, 48), dim3(512), 0, stream>>>(Iy, H);
        vpass_k<<<tile_g, tile_b, 0, stream>>>(H, Iy, xb);

        zeroi_k<<<16 * NBINS / 1024, 1024, 0, stream>>>(hist);
        hist2_k<<<hist_g, 1024, 0, stream>>>(xb, hist);
        quant_k<<<16, 1024, 0, stream>>>(hist, scal, 0.01f, 0.99f, 0, 1);
        nhat_k<<<NP / 1024, 256, 0, stream>>>(xb, scal);

        zeroi_k<<<16 * NBINS / 1024, 1024, 0, stream>>>(hist);
        gradhist2_k<<<hist_g, 1024, 0, stream>>>(xb, hist);
        quant_k<<<16, 1024, 0, stream>>>(hist, scal, 0.5f, 0.5f, 2, -1);
        w_k<<<tile_g, tile_b, 0, stream>>>(xb, scal, bx, by, pxA, pyA);

        const float* ucur = xb, *uprev = xb;
        float* Ubuf[3] = {U0, U1, out};
        float* pxs[2] = {pxA, pxB};
        float* pys[2] = {pyA, pyB};
        for (int t = 0; t < 30; ++t) {
            float* un = Ubuf[t % 3];
            int cur = t & 1;
            pdf_k<<<f4_g, tile_b, 0, stream>>>(ucur, uprev,
                                               pxs[cur], pys[cur],
                                               pxs[cur ^ 1], pys[cur ^ 1],
                                               bx, by, xb, un, (t == 29) ? 1 : 0);
            uprev = ucur;
            ucur = un;
        }
        // t=29 wrote clipped result into Ubuf[29%3] == out. Done.
    } else {
        // fallback: round-0 proven layout
        float* H   = ws;
        float* xb  = ws + (size_t)3 * NP;
        float* py  = ws + (size_t)4 * NP;
        float* U0  = ws + (size_t)5 * NP;
        float* U1  = ws + (size_t)6 * NP;
        float* U2  = ws + (size_t)7 * NP;
        int*   hist = (int*)(ws + (size_t)8 * NP);
        float* scal = ws + (size_t)8 * NP + 16 * NBINS;
        float* bx = H;
        float* by = H + (size_t)NP;
        float* px = H + (size_t)2 * NP;

        hpass_k<<<dim3(512, 48), dim3(512), 0, stream>>>(Iy, H);
        vpass_k<<<tile_g, tile_b, 0, stream>>>(H, Iy, xb);

        zeroi_k<<<16 * NBINS / 1024, 1024, 0, stream>>>(hist);
        hist2_k<<<hist_g, 1024, 0, stream>>>(xb, hist);
        quant_k<<<16, 1024, 0, stream>>>(hist, scal, 0.01f, 0.99f, 0, 1);
        nhat_k<<<NP / 1024, 256, 0, stream>>>(xb, scal);

        zeroi_k<<<16 * NBINS / 1024, 1024, 0, stream>>>(hist);
        gradhist2_k<<<hist_g, 1024, 0, stream>>>(xb, hist);
        quant_k<<<16, 1024, 0, stream>>>(hist, scal, 0.5f, 0.5f, 2, -1);
        w_k<<<tile_g, tile_b, 0, stream>>>(xb, scal, bx, by, px, py);

        const float* ucur = xb, *uprev = xb;
        float* Ubuf[3] = {U0, U1, U2};
        for (int t = 0; t < 30; ++t) {
            float* un = Ubuf[t % 3];
            pd1_k<<<tile_g, tile_b, 0, stream>>>(ucur, uprev, px, py, bx, by);
            pd2_k<<<tile_g, tile_b, 0, stream>>>(ucur, px, py, xb, un);
            uprev = ucur;
            ucur = un;
        }
        clip_k<<<NP / 1024, 256, 0, stream>>>(ucur, out);
    }
}

// Round 3
// 854.947 us; speedup vs baseline: 1.9944x; 1.3492x over previous
//
#include <hip/hip_runtime.h>
#include <hip/hip_bf16.h>
#include <hip/hip_fp16.h>
#include <math.h>

#define NPIX   262144          // 512*512
#define NP     4194304         // 16*512*512
#define NBINS  8192
#define HSUB   16
#define SIG    0.125f
#define TAUC   0.125f
#define ALPHAC 0.15f
#define MUC    10.0f
#define EPSC   1e-6f
#define NEGINF -3.4e38f

// ---------- helpers: 4-wide half load/store ----------
__device__ __forceinline__ void ld4h(const __half* p, float* d) {
    __half2 a = *(const __half2*)p;
    __half2 b = *(const __half2*)(p + 2);
    float2 fa = __half22float2(a), fb = __half22float2(b);
    d[0] = fa.x; d[1] = fa.y; d[2] = fb.x; d[3] = fb.y;
}

// ================= POOLING (vHGW separable max, M=max(G,B) fused) =================

// horizontal 31-max over rows, leader-thread prefix/suffix in LDS.
// m<16: R channel of batch m.  m>=16: max(G,B) of batch m-16.
__global__ __launch_bounds__(512) void hpass2_k(const float* __restrict__ Iy,
                                                float* __restrict__ H) {
    int y = blockIdx.x, m = blockIdx.y, tid = threadIdx.x;
    __shared__ float row[512], PP[512], SS[512];
    int b = m & 15;
    size_t base = (size_t)(b * 3) * NPIX + (size_t)y * 512;
    float val;
    if (m < 16) val = Iy[base + tid];
    else        val = fmaxf(Iy[base + NPIX + tid], Iy[base + 2 * (size_t)NPIX + tid]);
    row[tid] = val;
    __syncthreads();
    if (tid < 17) {
        int s0 = tid * 31;
        int len = min(31, 512 - s0);
        float s = NEGINF;
        for (int j = len - 1; j >= 0; --j) { s = fmaxf(s, row[s0 + j]); SS[s0 + j] = s; }
        float p = NEGINF;
        for (int j = 0; j < len; ++j) { p = fmaxf(p, row[s0 + j]); PP[s0 + j] = p; }
    }
    __syncthreads();
    int a = tid - 15, bb = tid + 15;
    float o;
    if (a < 0)        o = PP[bb];
    else if (bb > 511) o = fmaxf(SS[a], PP[511]);
    else              o = fmaxf(SS[a], PP[bb]);
    H[(size_t)m * NPIX + (size_t)y * 512 + tid] = o;
}

// vertical 31-max, per-thread register vHGW down columns.
// grid: (8 x-tiles, 9 y-chunks [2 segs each], 32 planes), block 64.
__global__ __launch_bounds__(64) void vpass2_k(const float* __restrict__ H,
                                               float* __restrict__ V) {
    int x = blockIdx.x * 64 + threadIdx.x;
    const float* in = H + (size_t)blockIdx.z * NPIX;
    float*      out = V + (size_t)blockIdx.z * NPIX;
    int c0 = blockIdx.y * 2;

    float Sprev[31];
    if (c0 > 0) {
        int s0 = (c0 - 1) * 31;      // always a full segment (<=15)
        float v[31];
#pragma unroll
        for (int j = 0; j < 31; ++j) v[j] = in[(size_t)(s0 + j) * 512 + x];
        float acc = NEGINF;
#pragma unroll
        for (int j = 30; j >= 0; --j) { acc = fmaxf(acc, v[j]); Sprev[j] = acc; }
    } else {
#pragma unroll
        for (int j = 0; j < 31; ++j) Sprev[j] = NEGINF;
    }

    int send = min(c0 + 1, 16);
    for (int s = c0; s <= send; ++s) {
        int s0 = s * 31;
        float v[31];
#pragma unroll
        for (int j = 0; j < 31; ++j)
            v[j] = (s0 + j < 512) ? in[(size_t)(s0 + j) * 512 + x] : NEGINF;
        float Scur[31];
        float acc = NEGINF;
#pragma unroll
        for (int j = 30; j >= 0; --j) { acc = fmaxf(acc, v[j]); Scur[j] = acc; }
        float P = NEGINF;
#pragma unroll
        for (int r = 0; r < 31; ++r) {
            P = fmaxf(P, v[r]);
            int i = s0 + r - 15;
            if (i >= 0 && i <= 511) {
                int a = s0 - 30 + r;
                float o;
                if (a < 0) o = P;
                else {
                    float Sv = (r == 30) ? Scur[0] : Sprev[r + 1];
                    o = fmaxf(Sv, P);
                }
                out[(size_t)i * 512 + x] = o;
            }
        }
#pragma unroll
        for (int j = 0; j < 31; ++j) Sprev[j] = Scur[j];
    }
}

// combine: xb = |VR - VM| + R   (float4)
__global__ __launch_bounds__(256) void combine_k(const float* __restrict__ V,
                                                 const float* __restrict__ Iy,
                                                 float* __restrict__ xb) {
    size_t i4 = ((size_t)blockIdx.x * 256 + threadIdx.x) * 4;
    int b = (int)(i4 >> 18);
    size_t off = i4 & (NPIX - 1);
    float4 vr = *(const float4*)(V + (size_t)b * NPIX + off);
    float4 vm = *(const float4*)(V + (size_t)(16 + b) * NPIX + off);
    float4 r  = *(const float4*)(Iy + (size_t)(b * 3) * NPIX + off);
    float4 o;
    o.x = fabsf(vr.x - vm.x) + r.x;
    o.y = fabsf(vr.y - vm.y) + r.y;
    o.z = fabsf(vr.z - vm.z) + r.z;
    o.w = fabsf(vr.w - vm.w) + r.w;
    *(float4*)(xb + i4) = o;
}

// ================= HISTOGRAM / QUANTILE =================

__global__ __launch_bounds__(1024) void zeroi_k(int* __restrict__ p) {
    p[blockIdx.x * 1024 + threadIdx.x] = 0;
}

__global__ __launch_bounds__(1024) void hist2_k(const float* __restrict__ v,
                                                int* __restrict__ hist) {
    __shared__ int lh[NBINS];
    int s = blockIdx.x, b = blockIdx.y, tid = threadIdx.x;
    for (int i = tid; i < NBINS; i += 1024) lh[i] = 0;
    __syncthreads();
    const float* p = v + (size_t)b * NPIX + (size_t)s * (NPIX / HSUB);
    for (int i = tid; i < NPIX / HSUB; i += 1024) {
        int bin = (int)(p[i] * (NBINS * 0.5f));
        bin = min(max(bin, 0), NBINS - 1);
        atomicAdd(&lh[bin], 1);
    }
    __syncthreads();
    for (int i = tid; i < NBINS; i += 1024) {
        int c = lh[i];
        if (c) atomicAdd(&hist[b * NBINS + i], c);
    }
}

__global__ __launch_bounds__(1024) void gradhist2_k(const float* __restrict__ nh,
                                                    int* __restrict__ hist) {
    __shared__ int lh[NBINS];
    int s = blockIdx.x, b = blockIdx.y, tid = threadIdx.x;
    for (int i = tid; i < NBINS; i += 1024) lh[i] = 0;
    __syncthreads();
    const float* p = nh + (size_t)b * NPIX;
    int base = s * (NPIX / HSUB);
    for (int ii = tid; ii < NPIX / HSUB; ii += 1024) {
        int i = base + ii;
        float c = p[i];
        int x = i & 511, y = i >> 9;
        float dx = (x < 511) ? p[i + 1]   - c : 0.f;
        float dy = (y < 511) ? p[i + 512] - c : 0.f;
        float gm = sqrtf(dx * dx + dy * dy + EPSC);
        int bin = (int)(gm * (NBINS * 0.5f));
        bin = min(max(bin, 0), NBINS - 1);
        atomicAdd(&lh[bin], 1);
    }
    __syncthreads();
    for (int i = tid; i < NBINS; i += 1024) {
        int c = lh[i];
        if (c) atomicAdd(&hist[b * NBINS + i], c);
    }
}

__global__ __launch_bounds__(1024) void quant_k(const int* __restrict__ hist,
                                                float* __restrict__ scal,
                                                float q0, float q1, int s0, int s1) {
    __shared__ int csum[1025];
    int b = blockIdx.x, tid = threadIdx.x;
    const int* h = hist + b * NBINS;
    int s = 0;
#pragma unroll
    for (int j = 0; j < NBINS / 1024; ++j) s += h[tid * (NBINS / 1024) + j];
    csum[tid] = s;
    __syncthreads();
    if (tid == 0) {
        int acc = 0;
        for (int i = 0; i < 1024; ++i) { int v = csum[i]; csum[i] = acc; acc += v; }
        csum[1024] = acc;
    }
    __syncthreads();
    if (tid < 2) {
        int slot = tid ? s1 : s0;
        if (slot >= 0) {
            float q = tid ? q1 : q0;
            float t = q * (float)(NPIX - 1);
            int chunk = 1023;
            for (int i = 0; i < 1024; ++i) {
                if ((float)csum[i + 1] > t) { chunk = i; break; }
            }
            int per = NBINS / 1024;
            int cb = csum[chunk];
            int bin = chunk * per;
            int hv = 1;
            for (int j = 0; j < per; ++j) {
                hv = h[chunk * per + j];
                if ((float)(cb + hv) > t) { bin = chunk * per + j; break; }
                cb += hv;
            }
            float k = t - (float)cb;
            float val = ((float)bin + (k + 0.5f) / (float)hv) * (2.0f / NBINS);
            scal[b * 4 + slot] = val;
        }
    }
}

__global__ __launch_bounds__(256) void nhat_k(float* __restrict__ xb,
                                              const float* __restrict__ scal) {
    size_t i = ((size_t)blockIdx.x * 256 + threadIdx.x) * 4;
    int b = (int)(i >> 18);
    float lo = scal[b * 4 + 0], hi = scal[b * 4 + 1];
    float inv = 1.0f / (hi - lo + EPSC);
    float4 v = *(const float4*)(xb + i);
    v.x = fminf(fmaxf((v.x - lo) * inv, 0.f), 1.f);
    v.y = fminf(fmaxf((v.y - lo) * inv, 0.f), 1.f);
    v.z = fminf(fmaxf((v.z - lo) * inv, 0.f), 1.f);
    v.w = fminf(fmaxf((v.w - lo) * inv, 0.f), 1.f);
    *(float4*)(xb + i) = v;
}

// ---------------- bounds (half) + zero p (half) ----------------
__global__ __launch_bounds__(256) void wh_k(const float* __restrict__ nh,
                                            const float* __restrict__ scal,
                                            __half* __restrict__ bx, __half* __restrict__ by,
                                            __half* __restrict__ px, __half* __restrict__ py) {
    int x = blockIdx.x * 64 + threadIdx.x;
    int y = blockIdx.y * 4  + threadIdx.y;
    int b = blockIdx.z;
    size_t base = (size_t)b * NPIX + (size_t)y * 512 + x;
    float c = nh[base];
    float dx = (x < 511) ? nh[base + 1]   - c : 0.f;
    float dy = (y < 511) ? nh[base + 512] - c : 0.f;
    float sgm = fmaxf(scal[b * 4 + 2], EPSC);
    float inv = 1.0f / sgm;
    bx[base] = __float2half_rn(ALPHAC * (1.f + MUC * expf(-fabsf(dx) * inv)));
    by[base] = __float2half_rn(ALPHAC * (1.f + MUC * expf(-fabsf(dy) * inv)));
    px[base] = __float2half_rn(0.f);
    py[base] = __float2half_rn(0.f);
}

// ---------------- fused PD iteration, p/b in fp16 ----------------
__global__ __launch_bounds__(256) void pdfh_k(const float* __restrict__ u,
                                              const float* __restrict__ up,
                                              const __half* __restrict__ pxO,
                                              const __half* __restrict__ pyO,
                                              __half* __restrict__ pxN,
                                              __half* __restrict__ pyN,
                                              const __half* __restrict__ bxA,
                                              const __half* __restrict__ byA,
                                              const float* __restrict__ nh,
                                              float* __restrict__ un,
                                              int last) {
    int x0 = (blockIdx.x * 64 + threadIdx.x) * 4;
    int y  = blockIdx.y * 4 + threadIdx.y;
    int b  = blockIdx.z;
    size_t base = (size_t)b * NPIX + (size_t)y * 512 + x0;
    bool hasD = (y < 511), hasU = (y > 0);

    float uc[4], upc[4], ud[4] = {0}, upd[4] = {0}, uu[4] = {0}, upu[4] = {0};
    { float4 t = *(const float4*)(u  + base); uc[0]=t.x; uc[1]=t.y; uc[2]=t.z; uc[3]=t.w; }
    { float4 t = *(const float4*)(up + base); upc[0]=t.x; upc[1]=t.y; upc[2]=t.z; upc[3]=t.w; }
    if (hasD) {
        float4 t = *(const float4*)(u  + base + 512); ud[0]=t.x; ud[1]=t.y; ud[2]=t.z; ud[3]=t.w;
        float4 s = *(const float4*)(up + base + 512); upd[0]=s.x; upd[1]=s.y; upd[2]=s.z; upd[3]=s.w;
    }
    if (hasU) {
        float4 t = *(const float4*)(u  + base - 512); uu[0]=t.x; uu[1]=t.y; uu[2]=t.z; uu[3]=t.w;
        float4 s = *(const float4*)(up + base - 512); upu[0]=s.x; upu[1]=s.y; upu[2]=s.z; upu[3]=s.w;
    }
    float bl = 0.f, br = 0.f;
    if (x0 > 0)   bl = 2.f * u[base - 1] - up[base - 1];
    if (x0 < 508) br = 2.f * u[base + 4] - up[base + 4];

    float bc[4], bd[4], bu[4];
#pragma unroll
    for (int i = 0; i < 4; ++i) {
        bc[i] = 2.f * uc[i] - upc[i];
        bd[i] = 2.f * ud[i] - upd[i];
        bu[i] = 2.f * uu[i] - upu[i];
    }

    float pxc[4], bxc[4], pyc[4], byc[4], pyu[4] = {0}, byu[4] = {0};
    ld4h(pxO + base, pxc);
    ld4h(bxA + base, bxc);
    ld4h(pyO + base, pyc);
    ld4h(byA + base, byc);
    if (hasU) {
        ld4h(pyO + base - 512, pyu);
        ld4h(byA + base - 512, byu);
    }

    float pxm1 = 0.f;
    if (x0 > 0) {
        float pxl = __half2float(pxO[base - 1]);
        float bxl = __half2float(bxA[base - 1]);
        float dxm1 = bc[0] - bl;
        pxm1 = __half2float(__float2half_rn(fminf(fmaxf(pxl + SIG * dxm1, -bxl), bxl)));
    }

    float pxn[4], pyn[4], pynU[4];
    __half pxh[4], pyh[4];
#pragma unroll
    for (int i = 0; i < 4; ++i) {
        float right = (i < 3) ? bc[i + 1] : br;
        float dx = (x0 + i < 511) ? right - bc[i] : 0.f;
        __half h = __float2half_rn(fminf(fmaxf(pxc[i] + SIG * dx, -bxc[i]), bxc[i]));
        pxh[i] = h; pxn[i] = __half2float(h);
        float dy = hasD ? bd[i] - bc[i] : 0.f;
        __half h2 = __float2half_rn(fminf(fmaxf(pyc[i] + SIG * dy, -byc[i]), byc[i]));
        pyh[i] = h2; pyn[i] = __half2float(h2);
        float dyU = bc[i] - bu[i];
        pynU[i] = __half2float(__float2half_rn(fminf(fmaxf(pyu[i] + SIG * dyU, -byu[i]), byu[i])));
    }

    *(__half2*)(pxN + base)     = __half2(pxh[0], pxh[1]);
    *(__half2*)(pxN + base + 2) = __half2(pxh[2], pxh[3]);
    *(__half2*)(pyN + base)     = __half2(pyh[0], pyh[1]);
    *(__half2*)(pyN + base + 2) = __half2(pyh[2], pyh[3]);

    float nhc[4];
    { float4 t = *(const float4*)(nh + base); nhc[0]=t.x; nhc[1]=t.y; nhc[2]=t.z; nhc[3]=t.w; }
    float unew[4];
#pragma unroll
    for (int i = 0; i < 4; ++i) {
        float left = (i > 0) ? pxn[i - 1] : pxm1;
        float div = pxn[i] + pyn[i] - left - (hasU ? pynU[i] : 0.f);
        float v = (uc[i] + TAUC * div + TAUC * nhc[i]) * (1.0f / (1.0f + TAUC));
        if (last) v = fminf(fmaxf(v, 0.f), 1.f);
        unew[i] = v;
    }
    *(float4*)(un + base) = make_float4(unew[0], unew[1], unew[2], unew[3]);
}

// ================= FALLBACK (round-1 proven, fp32 everything) =================

__global__ __launch_bounds__(512) void hpass_k(const float* __restrict__ in,
                                               float* __restrict__ out) {
    int y  = blockIdx.x;
    int bc = blockIdx.y;
    int tid = threadIdx.x;
    __shared__ float row[512];
    size_t ibase = (size_t)bc * NPIX + (size_t)y * 512;
    row[tid] = in[ibase + tid];
    __syncthreads();
    int lo = max(tid - 15, 0), hi = min(tid + 15, 511);
    float m = NEGINF;
    for (int i = lo; i <= hi; ++i) m = fmaxf(m, row[i]);
    int b = bc / 3, c = bc % 3;
    out[((size_t)c * 16 + b) * NPIX + (size_t)y * 512 + tid] = m;
}

__global__ __launch_bounds__(256) void vpass_k(const float* __restrict__ H,
                                               const float* __restrict__ Iy,
                                               float* __restrict__ xb) {
    int x = blockIdx.x * 64 + threadIdx.x;
    int y = blockIdx.y * 4  + threadIdx.y;
    int b = blockIdx.z;
    const float* HR = H + (size_t)(0 * 16 + b) * NPIX;
    const float* HG = H + (size_t)(1 * 16 + b) * NPIX;
    const float* HB = H + (size_t)(2 * 16 + b) * NPIX;
    int y0 = max(y - 15, 0), y1 = min(y + 15, 511);
    float mr = NEGINF, mg = NEGINF, mb = NEGINF;
    for (int yy = y0; yy <= y1; ++yy) {
        int o = yy * 512 + x;
        mr = fmaxf(mr, HR[o]);
        mg = fmaxf(mg, HG[o]);
        mb = fmaxf(mb, HB[o]);
    }
    float R = Iy[(size_t)(b * 3) * NPIX + (size_t)y * 512 + x];
    xb[(size_t)b * NPIX + (size_t)y * 512 + x] = fabsf(mr - fmaxf(mg, mb)) + R;
}

__global__ __launch_bounds__(256) void w_k(const float* __restrict__ nh,
                                           const float* __restrict__ scal,
                                           float* __restrict__ bx, float* __restrict__ by,
                                           float* __restrict__ px, float* __restrict__ py) {
    int x = blockIdx.x * 64 + threadIdx.x;
    int y = blockIdx.y * 4  + threadIdx.y;
    int b = blockIdx.z;
    size_t base = (size_t)b * NPIX + (size_t)y * 512 + x;
    float c = nh[base];
    float dx = (x < 511) ? nh[base + 1]   - c : 0.f;
    float dy = (y < 511) ? nh[base + 512] - c : 0.f;
    float sgm = fmaxf(scal[b * 4 + 2], EPSC);
    float inv = 1.0f / sgm;
    bx[base] = ALPHAC * (1.f + MUC * expf(-fabsf(dx) * inv));
    by[base] = ALPHAC * (1.f + MUC * expf(-fabsf(dy) * inv));
    px[base] = 0.f;
    py[base] = 0.f;
}

__global__ __launch_bounds__(256) void pd1_k(const float* __restrict__ u,
                                             const float* __restrict__ up,
                                             float* __restrict__ px, float* __restrict__ py,
                                             const float* __restrict__ bx,
                                             const float* __restrict__ by) {
    int x = blockIdx.x * 64 + threadIdx.x;
    int y = blockIdx.y * 4  + threadIdx.y;
    int b = blockIdx.z;
    size_t base = (size_t)b * NPIX + (size_t)y * 512 + x;
    float ubc = 2.f * u[base] - up[base];
    float dx = 0.f, dy = 0.f;
    if (x < 511) { float r = 2.f * u[base + 1]   - up[base + 1];   dx = r - ubc; }
    if (y < 511) { float d = 2.f * u[base + 512] - up[base + 512]; dy = d - ubc; }
    float bxv = bx[base], byv = by[base];
    float pxv = px[base] + SIG * dx;
    float pyv = py[base] + SIG * dy;
    px[base] = fminf(fmaxf(pxv, -bxv), bxv);
    py[base] = fminf(fmaxf(pyv, -byv), byv);
}

__global__ __launch_bounds__(256) void pd2_k(const float* __restrict__ u,
                                             const float* __restrict__ px,
                                             const float* __restrict__ py,
                                             const float* __restrict__ nh,
                                             float* __restrict__ un) {
    int x = blockIdx.x * 64 + threadIdx.x;
    int y = blockIdx.y * 4  + threadIdx.y;
    int b = blockIdx.z;
    size_t base = (size_t)b * NPIX + (size_t)y * 512 + x;
    float div = px[base] + py[base];
    if (x > 0) div -= px[base - 1];
    if (y > 0) div -= py[base - 512];
    float v = u[base] + TAUC * div;
    un[base] = (v + TAUC * nh[base]) * (1.0f / (1.0f + TAUC));
}

__global__ __launch_bounds__(256) void clip_k(const float* __restrict__ u,
                                              float* __restrict__ out) {
    size_t i = ((size_t)blockIdx.x * 256 + threadIdx.x) * 4;
    float4 v = *(const float4*)(u + i);
    v.x = fminf(fmaxf(v.x, 0.f), 1.f);
    v.y = fminf(fmaxf(v.y, 0.f), 1.f);
    v.z = fminf(fmaxf(v.z, 0.f), 1.f);
    v.w = fminf(fmaxf(v.w, 0.f), 1.f);
    *(float4*)(out + i) = v;
}

extern "C" void kernel_launch(void* const* d_in, const int* in_sizes, int n_in,
                              void* d_out, int out_size, void* d_ws, size_t ws_size,
                              hipStream_t stream) {
    const float* Iy = (const float*)d_in[0];
    float* ws = (float*)d_ws;
    float* out = (float*)d_out;

    dim3 tile_b(64, 4), tile_g(8, 128, 16);   // scalar per-px kernels
    dim3 f4_g(2, 128, 16);                    // float4 kernels
    dim3 hist_g(HSUB, 16);

    size_t need_fused = (size_t)9 * NP * 4 + (size_t)16 * NBINS * 4 + 256;

    if (ws_size >= need_fused) {
        // layout (float units):
        // 0:xb | NP:U0 | 2NP:U1 | 3NP:bxh,byh | 4NP:pxAh,pyAh | 5NP:pxBh,pyBh
        // 6NP:H(2NP) | 8NP:hist,scal        V(2NP) transient at NP..3NP
        float*  xb  = ws;
        float*  U0  = ws + (size_t)NP;
        float*  U1  = ws + (size_t)2 * NP;
        __half* bxh = (__half*)(ws + (size_t)3 * NP);
        __half* byh = (__half*)(ws + (size_t)3 * NP + NP / 2);
        __half* pxA = (__half*)(ws + (size_t)4 * NP);
        __half* pyA = (__half*)(ws + (size_t)4 * NP + NP / 2);
        __half* pxB = (__half*)(ws + (size_t)5 * NP);
        __half* pyB = (__half*)(ws + (size_t)5 * NP + NP / 2);
        float*  H   = ws + (size_t)6 * NP;    // 2NP
        float*  V   = ws + (size_t)NP;        // 2NP transient (U0,U1 region)
        int*    hist = (int*)(ws + (size_t)8 * NP);
        float*  scal = ws + (size_t)8 * NP + 16 * NBINS;

        // 1. separable 31x31 max pool (R and M=max(G,B)) + Dmip combine
        hpass2_k<<<dim3(512, 32), dim3(512), 0, stream>>>(Iy, H);
        vpass2_k<<<dim3(8, 9, 32), dim3(64), 0, stream>>>(H, V);
        combine_k<<<NP / 1024, 256, 0, stream>>>(V, Iy, xb);

        // 2. robust normalize
        zeroi_k<<<16 * NBINS / 1024, 1024, 0, stream>>>(hist);
        hist2_k<<<hist_g, 1024, 0, stream>>>(xb, hist);
        quant_k<<<16, 1024, 0, stream>>>(hist, scal, 0.01f, 0.99f, 0, 1);
        nhat_k<<<NP / 1024, 256, 0, stream>>>(xb, scal);

        // 3. sigma (median grad mag) -> fp16 bounds, zero fp16 p
        zeroi_k<<<16 * NBINS / 1024, 1024, 0, stream>>>(hist);
        gradhist2_k<<<hist_g, 1024, 0, stream>>>(xb, hist);
        quant_k<<<16, 1024, 0, stream>>>(hist, scal, 0.5f, 0.5f, 2, -1);
        wh_k<<<tile_g, tile_b, 0, stream>>>(xb, scal, bxh, byh, pxA, pyA);

        // 4. 30 fused PD iterations (u_bar = 2u - u_prev)
        const float* ucur = xb, *uprev = xb;
        float* Ubuf[3] = {U0, U1, out};
        __half* pxs[2] = {pxA, pxB};
        __half* pys[2] = {pyA, pyB};
        for (int t = 0; t < 30; ++t) {
            float* un = Ubuf[t % 3];
            int cur = t & 1;
            pdfh_k<<<f4_g, tile_b, 0, stream>>>(ucur, uprev,
                                                pxs[cur], pys[cur],
                                                pxs[cur ^ 1], pys[cur ^ 1],
                                                bxh, byh, xb, un, (t == 29) ? 1 : 0);
            uprev = ucur;
            ucur = un;
        }
        // t=29 wrote clipped result into Ubuf[29%3] == out.
    } else {
        // fallback: round-1 proven path
        float* H   = ws;
        float* xb  = ws + (size_t)3 * NP;
        float* py  = ws + (size_t)4 * NP;
        float* U0  = ws + (size_t)5 * NP;
        float* U1  = ws + (size_t)6 * NP;
        float* U2  = ws + (size_t)7 * NP;
        int*   hist = (int*)(ws + (size_t)8 * NP);
        float* scal = ws + (size_t)8 * NP + 16 * NBINS;
        float* bx = H;
        float* by = H + (size_t)NP;
        float* px = H + (size_t)2 * NP;

        hpass_k<<<dim3(512, 48), dim3(512), 0, stream>>>(Iy, H);
        vpass_k<<<tile_g, tile_b, 0, stream>>>(H, Iy, xb);

        zeroi_k<<<16 * NBINS / 1024, 1024, 0, stream>>>(hist);
        hist2_k<<<hist_g, 1024, 0, stream>>>(xb, hist);
        quant_k<<<16, 1024, 0, stream>>>(hist, scal, 0.01f, 0.99f, 0, 1);
        nhat_k<<<NP / 1024, 256, 0, stream>>>(xb, scal);

        zeroi_k<<<16 * NBINS / 1024, 1024, 0, stream>>>(hist);
        gradhist2_k<<<hist_g, 1024, 0, stream>>>(xb, hist);
        quant_k<<<16, 1024, 0, stream>>>(hist, scal, 0.5f, 0.5f, 2, -1);
        w_k<<<tile_g, tile_b, 0, stream>>>(xb, scal, bx, by, px, py);

        const float* ucur = xb, *uprev = xb;
        float* Ubuf[3] = {U0, U1, U2};
        for (int t = 0; t < 30; ++t) {
            float* un = Ubuf[t % 3];
            pd1_k<<<tile_g, tile_b, 0, stream>>>(ucur, uprev, px, py, bx, by);
            pd2_k<<<tile_g, tile_b, 0, stream>>>(ucur, px, py, xb, un);
            uprev = ucur;
            ucur = un;
        }
        clip_k<<<NP / 1024, 256, 0, stream>>>(ucur, out);
    }
}

// Round 4
// 779.170 us; speedup vs baseline: 2.1883x; 1.0973x over previous
//
#include <hip/hip_runtime.h>
#include <hip/hip_bf16.h>
#include <hip/hip_fp16.h>
#include <math.h>

#define NPIX   262144          // 512*512
#define NP     4194304         // 16*512*512
#define NBINS  8192
#define HSUB   16
#define SIG    0.125f
#define TAUC   0.125f
#define ALPHAC 0.15f
#define MUC    10.0f
#define EPSC   1e-6f
#define NEGINF -3.4e38f

// ---------- helpers: 4-wide half load ----------
__device__ __forceinline__ void ld4h(const __half* p, float* d) {
    __half2 a = *(const __half2*)p;
    __half2 b = *(const __half2*)(p + 2);
    float2 fa = __half22float2(a), fb = __half22float2(b);
    d[0] = fa.x; d[1] = fa.y; d[2] = fb.x; d[3] = fb.y;
}

// ================= POOLING =================

// horizontal 31-max over rows, fully parallel per-thread segment scans.
// m<16: R channel of batch m.  m>=16: max(G,B) of batch m-16.
__global__ __launch_bounds__(512) void hpass2_k(const float* __restrict__ Iy,
                                                float* __restrict__ H) {
    int y = blockIdx.x, m = blockIdx.y, tid = threadIdx.x;
    __shared__ float row[512], PP[512], SS[512];
    int b = m & 15;
    size_t base = (size_t)(b * 3) * NPIX + (size_t)y * 512;
    float val;
    if (m < 16) val = Iy[base + tid];
    else        val = fmaxf(Iy[base + NPIX + tid], Iy[base + 2 * (size_t)NPIX + tid]);
    row[tid] = val;
    __syncthreads();
    int s0 = (tid / 31) * 31;
    int s1 = min(s0 + 30, 511);
    float p = val;
    for (int j = tid - 1; j >= s0; --j) p = fmaxf(p, row[j]);
    PP[tid] = p;
    float s = val;
    for (int j = tid + 1; j <= s1; ++j) s = fmaxf(s, row[j]);
    SS[tid] = s;
    __syncthreads();
    int a = tid - 15, bb = tid + 15;
    float o;
    if (a < 0)         o = PP[bb];
    else if (bb > 511) o = fmaxf(SS[a], PP[511]);
    else               o = fmaxf(SS[a], PP[bb]);
    H[(size_t)m * NPIX + (size_t)y * 512 + tid] = o;
}

// vertical 31-max on BOTH planes (R and M) + combine into xb = |vR - vM| + R.
// grid: (8 x-tiles, 9 y-chunks [2 segs each], 16 batches), block 64.
__global__ __launch_bounds__(64) void vpassC_k(const float* __restrict__ H,
                                               const float* __restrict__ Iy,
                                               float* __restrict__ xb) {
    int x = blockIdx.x * 64 + threadIdx.x;
    int b = blockIdx.z;
    const float* inR = H + (size_t)b * NPIX;
    const float* inM = H + (size_t)(16 + b) * NPIX;
    const float* IyR = Iy + (size_t)(b * 3) * NPIX;
    float*       out = xb + (size_t)b * NPIX;
    int c0 = blockIdx.y * 2;

    float SprevR[31], SprevM[31];
    if (c0 > 0) {
        int s0 = (c0 - 1) * 31;      // always a full segment
        float vR[31], vM[31];
#pragma unroll
        for (int j = 0; j < 31; ++j) {
            vR[j] = inR[(size_t)(s0 + j) * 512 + x];
            vM[j] = inM[(size_t)(s0 + j) * 512 + x];
        }
        float aR = NEGINF, aM = NEGINF;
#pragma unroll
        for (int j = 30; j >= 0; --j) {
            aR = fmaxf(aR, vR[j]); SprevR[j] = aR;
            aM = fmaxf(aM, vM[j]); SprevM[j] = aM;
        }
    } else {
#pragma unroll
        for (int j = 0; j < 31; ++j) { SprevR[j] = NEGINF; SprevM[j] = NEGINF; }
    }

    int send = min(c0 + 1, 16);
    for (int s = c0; s <= send; ++s) {
        int s0 = s * 31;
        float vR[31], vM[31];
#pragma unroll
        for (int j = 0; j < 31; ++j) {
            bool ok = (s0 + j < 512);
            vR[j] = ok ? inR[(size_t)(s0 + j) * 512 + x] : NEGINF;
            vM[j] = ok ? inM[(size_t)(s0 + j) * 512 + x] : NEGINF;
        }
        float ScurR[31], ScurM[31];
        float aR = NEGINF, aM = NEGINF;
#pragma unroll
        for (int j = 30; j >= 0; --j) {
            aR = fmaxf(aR, vR[j]); ScurR[j] = aR;
            aM = fmaxf(aM, vM[j]); ScurM[j] = aM;
        }
        float PR = NEGINF, PM = NEGINF;
#pragma unroll
        for (int r = 0; r < 31; ++r) {
            PR = fmaxf(PR, vR[r]);
            PM = fmaxf(PM, vM[r]);
            int i = s0 + r - 15;
            if (i >= 0 && i <= 511) {
                int a = s0 - 30 + r;
                float oR, oM;
                if (a < 0) { oR = PR; oM = PM; }
                else {
                    float SvR = (r == 30) ? ScurR[0] : SprevR[r + 1];
                    float SvM = (r == 30) ? ScurM[0] : SprevM[r + 1];
                    oR = fmaxf(SvR, PR);
                    oM = fmaxf(SvM, PM);
                }
                out[(size_t)i * 512 + x] = fabsf(oR - oM) + IyR[(size_t)i * 512 + x];
            }
        }
#pragma unroll
        for (int j = 0; j < 31; ++j) { SprevR[j] = ScurR[j]; SprevM[j] = ScurM[j]; }
    }
}

// ================= HISTOGRAM / QUANTILE =================

__global__ __launch_bounds__(1024) void zeroi_k(int* __restrict__ p) {
    p[blockIdx.x * 1024 + threadIdx.x] = 0;
}

__global__ __launch_bounds__(1024) void hist2_k(const float* __restrict__ v,
                                                int* __restrict__ hist) {
    __shared__ int lh[NBINS];
    int s = blockIdx.x, b = blockIdx.y, tid = threadIdx.x;
    for (int i = tid; i < NBINS; i += 1024) lh[i] = 0;
    __syncthreads();
    const float* p = v + (size_t)b * NPIX + (size_t)s * (NPIX / HSUB);
    for (int i = tid; i < NPIX / HSUB; i += 1024) {
        int bin = (int)(p[i] * (NBINS * 0.5f));
        bin = min(max(bin, 0), NBINS - 1);
        atomicAdd(&lh[bin], 1);
    }
    __syncthreads();
    for (int i = tid; i < NBINS; i += 1024) {
        int c = lh[i];
        if (c) atomicAdd(&hist[b * NBINS + i], c);
    }
}

// histogram of gradient magnitude of fp16 N_hat
__global__ __launch_bounds__(1024) void gradhisth_k(const __half* __restrict__ nh,
                                                    int* __restrict__ hist) {
    __shared__ int lh[NBINS];
    int s = blockIdx.x, b = blockIdx.y, tid = threadIdx.x;
    for (int i = tid; i < NBINS; i += 1024) lh[i] = 0;
    __syncthreads();
    const __half* p = nh + (size_t)b * NPIX;
    int base = s * (NPIX / HSUB);
    for (int ii = tid; ii < NPIX / HSUB; ii += 1024) {
        int i = base + ii;
        float c = __half2float(p[i]);
        int x = i & 511, y = i >> 9;
        float dx = (x < 511) ? __half2float(p[i + 1])   - c : 0.f;
        float dy = (y < 511) ? __half2float(p[i + 512]) - c : 0.f;
        float gm = sqrtf(dx * dx + dy * dy + EPSC);
        int bin = (int)(gm * (NBINS * 0.5f));
        bin = min(max(bin, 0), NBINS - 1);
        atomicAdd(&lh[bin], 1);
    }
    __syncthreads();
    for (int i = tid; i < NBINS; i += 1024) {
        int c = lh[i];
        if (c) atomicAdd(&hist[b * NBINS + i], c);
    }
}

__global__ __launch_bounds__(1024) void quant_k(const int* __restrict__ hist,
                                                float* __restrict__ scal,
                                                float q0, float q1, int s0, int s1) {
    __shared__ int csum[1025];
    int b = blockIdx.x, tid = threadIdx.x;
    const int* h = hist + b * NBINS;
    int s = 0;
#pragma unroll
    for (int j = 0; j < NBINS / 1024; ++j) s += h[tid * (NBINS / 1024) + j];
    csum[tid] = s;
    __syncthreads();
    if (tid == 0) {
        int acc = 0;
        for (int i = 0; i < 1024; ++i) { int v = csum[i]; csum[i] = acc; acc += v; }
        csum[1024] = acc;
    }
    __syncthreads();
    if (tid < 2) {
        int slot = tid ? s1 : s0;
        if (slot >= 0) {
            float q = tid ? q1 : q0;
            float t = q * (float)(NPIX - 1);
            int chunk = 1023;
            for (int i = 0; i < 1024; ++i) {
                if ((float)csum[i + 1] > t) { chunk = i; break; }
            }
            int per = NBINS / 1024;
            int cb = csum[chunk];
            int bin = chunk * per;
            int hv = 1;
            for (int j = 0; j < per; ++j) {
                hv = h[chunk * per + j];
                if ((float)(cb + hv) > t) { bin = chunk * per + j; break; }
                cb += hv;
            }
            float k = t - (float)cb;
            float val = ((float)bin + (k + 0.5f) / (float)hv) * (2.0f / NBINS);
            scal[b * 4 + slot] = val;
        }
    }
}

// ---------------- N_hat (fp16) from xb (fp32) ----------------
__global__ __launch_bounds__(256) void nhat2h_k(const float* __restrict__ xb,
                                                const float* __restrict__ scal,
                                                __half* __restrict__ nhh) {
    size_t i = ((size_t)blockIdx.x * 256 + threadIdx.x) * 4;
    int b = (int)(i >> 18);
    float lo = scal[b * 4 + 0], hi = scal[b * 4 + 1];
    float inv = 1.0f / (hi - lo + EPSC);
    float4 v = *(const float4*)(xb + i);
    float a0 = fminf(fmaxf((v.x - lo) * inv, 0.f), 1.f);
    float a1 = fminf(fmaxf((v.y - lo) * inv, 0.f), 1.f);
    float a2 = fminf(fmaxf((v.z - lo) * inv, 0.f), 1.f);
    float a3 = fminf(fmaxf((v.w - lo) * inv, 0.f), 1.f);
    *(__half2*)(nhh + i)     = __floats2half2_rn(a0, a1);
    *(__half2*)(nhh + i + 2) = __floats2half2_rn(a2, a3);
}

// ---------------- bounds (half) + zero p (half), from fp16 nh ----------------
__global__ __launch_bounds__(256) void whh_k(const __half* __restrict__ nh,
                                             const float* __restrict__ scal,
                                             __half* __restrict__ bx, __half* __restrict__ by,
                                             __half* __restrict__ px, __half* __restrict__ py) {
    int x = blockIdx.x * 64 + threadIdx.x;
    int y = blockIdx.y * 4  + threadIdx.y;
    int b = blockIdx.z;
    size_t base = (size_t)b * NPIX + (size_t)y * 512 + x;
    float c = __half2float(nh[base]);
    float dx = (x < 511) ? __half2float(nh[base + 1])   - c : 0.f;
    float dy = (y < 511) ? __half2float(nh[base + 512]) - c : 0.f;
    float sgm = fmaxf(scal[b * 4 + 2], EPSC);
    float inv = 1.0f / sgm;
    bx[base] = __float2half_rn(ALPHAC * (1.f + MUC * expf(-fabsf(dx) * inv)));
    by[base] = __float2half_rn(ALPHAC * (1.f + MUC * expf(-fabsf(dy) * inv)));
    px[base] = __float2half_rn(0.f);
    py[base] = __float2half_rn(0.f);
}

// ---------------- fused PD iteration, everything fp16 in memory ----------------
__global__ __launch_bounds__(256) void pdfh2_k(const __half* __restrict__ u,
                                               const __half* __restrict__ up,
                                               const __half* __restrict__ pxO,
                                               const __half* __restrict__ pyO,
                                               __half* __restrict__ pxN,
                                               __half* __restrict__ pyN,
                                               const __half* __restrict__ bxA,
                                               const __half* __restrict__ byA,
                                               const __half* __restrict__ nh,
                                               __half* __restrict__ un,
                                               float* __restrict__ outF,
                                               int last) {
    int x0 = (blockIdx.x * 64 + threadIdx.x) * 4;
    int y  = blockIdx.y * 4 + threadIdx.y;
    int b  = blockIdx.z;
    size_t base = (size_t)b * NPIX + (size_t)y * 512 + x0;
    bool hasD = (y < 511), hasU = (y > 0);

    float uc[4], upc[4], ud[4] = {0,0,0,0}, upd[4] = {0,0,0,0}, uu[4] = {0,0,0,0}, upu[4] = {0,0,0,0};
    ld4h(u + base, uc); ld4h(up + base, upc);
    if (hasD) { ld4h(u + base + 512, ud); ld4h(up + base + 512, upd); }
    if (hasU) { ld4h(u + base - 512, uu); ld4h(up + base - 512, upu); }
    float bl = 0.f, br = 0.f;
    if (x0 > 0)   bl = 2.f * __half2float(u[base - 1]) - __half2float(up[base - 1]);
    if (x0 < 508) br = 2.f * __half2float(u[base + 4]) - __half2float(up[base + 4]);

    float bc[4], bd[4], bu[4];
#pragma unroll
    for (int i = 0; i < 4; ++i) {
        bc[i] = 2.f * uc[i] - upc[i];
        bd[i] = 2.f * ud[i] - upd[i];
        bu[i] = 2.f * uu[i] - upu[i];
    }

    float pxc[4], bxc[4], pyc[4], byc[4], pyu[4] = {0,0,0,0}, byu[4] = {0,0,0,0};
    ld4h(pxO + base, pxc); ld4h(bxA + base, bxc);
    ld4h(pyO + base, pyc); ld4h(byA + base, byc);
    if (hasU) { ld4h(pyO + base - 512, pyu); ld4h(byA + base - 512, byu); }

    float pxm1 = 0.f;
    if (x0 > 0) {
        float pxl = __half2float(pxO[base - 1]);
        float bxl = __half2float(bxA[base - 1]);
        pxm1 = __half2float(__float2half_rn(fminf(fmaxf(pxl + SIG * (bc[0] - bl), -bxl), bxl)));
    }

    float pxn[4], pyn[4], pynU[4];
    __half pxh[4], pyh[4];
#pragma unroll
    for (int i = 0; i < 4; ++i) {
        float right = (i < 3) ? bc[i + 1] : br;
        float dx = (x0 + i < 511) ? right - bc[i] : 0.f;
        __half h = __float2half_rn(fminf(fmaxf(pxc[i] + SIG * dx, -bxc[i]), bxc[i]));
        pxh[i] = h; pxn[i] = __half2float(h);
        float dy = hasD ? bd[i] - bc[i] : 0.f;
        __half h2 = __float2half_rn(fminf(fmaxf(pyc[i] + SIG * dy, -byc[i]), byc[i]));
        pyh[i] = h2; pyn[i] = __half2float(h2);
        float dyU = bc[i] - bu[i];
        pynU[i] = __half2float(__float2half_rn(fminf(fmaxf(pyu[i] + SIG * dyU, -byu[i]), byu[i])));
    }

    if (!last) {
        *(__half2*)(pxN + base)     = __half2(pxh[0], pxh[1]);
        *(__half2*)(pxN + base + 2) = __half2(pxh[2], pxh[3]);
        *(__half2*)(pyN + base)     = __half2(pyh[0], pyh[1]);
        *(__half2*)(pyN + base + 2) = __half2(pyh[2], pyh[3]);
    }

    float nhc[4]; ld4h(nh + base, nhc);
    float unew[4];
#pragma unroll
    for (int i = 0; i < 4; ++i) {
        float left = (i > 0) ? pxn[i - 1] : pxm1;
        float div = pxn[i] + pyn[i] - left - (hasU ? pynU[i] : 0.f);
        unew[i] = (uc[i] + TAUC * div + TAUC * nhc[i]) * (1.0f / (1.0f + TAUC));
    }
    if (last) {
        float4 o;
        o.x = fminf(fmaxf(unew[0], 0.f), 1.f);
        o.y = fminf(fmaxf(unew[1], 0.f), 1.f);
        o.z = fminf(fmaxf(unew[2], 0.f), 1.f);
        o.w = fminf(fmaxf(unew[3], 0.f), 1.f);
        *(float4*)(outF + base) = o;
    } else {
        *(__half2*)(un + base)     = __floats2half2_rn(unew[0], unew[1]);
        *(__half2*)(un + base + 2) = __floats2half2_rn(unew[2], unew[3]);
    }
}

extern "C" void kernel_launch(void* const* d_in, const int* in_sizes, int n_in,
                              void* d_out, int out_size, void* d_ws, size_t ws_size,
                              hipStream_t stream) {
    const float* Iy = (const float*)d_in[0];
    float* ws = (float*)d_ws;
    float* out = (float*)d_out;

    dim3 tile_b(64, 4), tile_g(8, 128, 16);   // 1 px/thread kernels
    dim3 f4_g(2, 128, 16);                    // 4 px/thread kernels
    dim3 hist_g(HSUB, 16);

    // layout (float units):
    // 0..NP: xb (fp32) | NP..3NP: H (2 planes fp32) | 3NP..8NP: fp16 arrays | 8NP: hist,scal
    float*  xb = ws;
    float*  H  = ws + (size_t)NP;
    __half* hb = (__half*)(ws + (size_t)3 * NP);
    __half* nhh = hb;
    __half* HA  = hb + (size_t)NP;
    __half* HB  = hb + (size_t)2 * NP;
    __half* HC  = hb + (size_t)3 * NP;
    __half* bxh = hb + (size_t)4 * NP;
    __half* byh = hb + (size_t)5 * NP;
    __half* pxA = hb + (size_t)6 * NP;
    __half* pyA = hb + (size_t)7 * NP;
    __half* pxB = hb + (size_t)8 * NP;
    __half* pyB = hb + (size_t)9 * NP;
    int*    hist = (int*)(ws + (size_t)8 * NP);
    float*  scal = ws + (size_t)8 * NP + 16 * NBINS;

    // 1. separable 31x31 max pool (R and M=max(G,B)) fused with Dmip combine
    hpass2_k<<<dim3(512, 32), dim3(512), 0, stream>>>(Iy, H);
    vpassC_k<<<dim3(8, 9, 16), dim3(64), 0, stream>>>(H, Iy, xb);

    // 2. robust normalize -> fp16 N_hat
    zeroi_k<<<16 * NBINS / 1024, 1024, 0, stream>>>(hist);
    hist2_k<<<hist_g, 1024, 0, stream>>>(xb, hist);
    quant_k<<<16, 1024, 0, stream>>>(hist, scal, 0.01f, 0.99f, 0, 1);
    nhat2h_k<<<NP / 1024, 256, 0, stream>>>(xb, scal, nhh);

    // 3. sigma (median grad mag) -> fp16 bounds, zero fp16 p
    zeroi_k<<<16 * NBINS / 1024, 1024, 0, stream>>>(hist);
    gradhisth_k<<<hist_g, 1024, 0, stream>>>(nhh, hist);
    quant_k<<<16, 1024, 0, stream>>>(hist, scal, 0.5f, 0.5f, 2, -1);
    whh_k<<<tile_g, tile_b, 0, stream>>>(nhh, scal, bxh, byh, pxA, pyA);

    // 4. 30 fused PD iterations (u_bar = 2u - u_prev), all-fp16 state
    const __half* ucur = nhh;
    const __half* uprev = nhh;
    __half* Ubuf[3] = {HA, HB, HC};
    __half* pxs[2] = {pxA, pxB};
    __half* pys[2] = {pyA, pyB};
    for (int t = 0; t < 30; ++t) {
        __half* un = Ubuf[t % 3];
        int cur = t & 1;
        pdfh2_k<<<f4_g, tile_b, 0, stream>>>(ucur, uprev,
                                             pxs[cur], pys[cur],
                                             pxs[cur ^ 1], pys[cur ^ 1],
                                             bxh, byh, nhh, un, out, (t == 29) ? 1 : 0);
        uprev = ucur;
        ucur = un;
    }
    // t=29 wrote clipped fp32 result directly to out.
}

// Round 5
// 742.632 us; speedup vs baseline: 2.2960x; 1.0492x over previous
//
#include <hip/hip_runtime.h>
#include <hip/hip_bf16.h>
#include <hip/hip_fp16.h>
#include <math.h>

#define NPIX   262144          // 512*512
#define NP     4194304         // 16*512*512
#define NBINS  8192
#define HSUB   16
#define SIG    0.125f
#define TAUC   0.125f
#define ALPHAC 0.15f
#define MUC    10.0f
#define EPSC   1e-6f
#define NEGINF -3.4e38f

// ---------- helpers ----------
__device__ __forceinline__ void ld4h(const __half* p, float* d) {
    __half2 a = *(const __half2*)p;
    __half2 b = *(const __half2*)(p + 2);
    float2 fa = __half22float2(a), fb = __half22float2(b);
    d[0] = fa.x; d[1] = fa.y; d[2] = fb.x; d[3] = fb.y;
}
__device__ __forceinline__ float bnd(float d, float inv) {
    return ALPHAC * (1.f + MUC * __expf(-fabsf(d) * inv));
}

// ================= POOLING =================

// horizontal 31-max, 3-phase vHGW: coalesced stage -> parallel register scans -> combine.
// plane<16: R of batch plane. plane>=16: max(G,B) of batch plane-16.
// grid (64 rowgroups, 32 planes), block 512.
__global__ __launch_bounds__(512) void hpass3_k(const float* __restrict__ Iy,
                                                float* __restrict__ H) {
    __shared__ float rowbuf[8][512];
    __shared__ float PB[8][512];
    __shared__ float SB[8][512];
    int tid = threadIdx.x;
    int plane = blockIdx.y;
    int y0 = blockIdx.x * 8;

    // --- stage 8 rows, float4-coalesced ---
#pragma unroll
    for (int q = 0; q < 2; ++q) {
        int idx = q * 512 + tid;          // float4 unit in [0,1024)
        int r = idx >> 7;
        int x4 = (idx & 127) << 2;
        float4 v;
        if (plane < 16) {
            v = *(const float4*)(Iy + (size_t)(plane * 3) * NPIX + (size_t)(y0 + r) * 512 + x4);
        } else {
            int b = plane - 16;
            float4 g = *(const float4*)(Iy + ((size_t)(b * 3) + 1) * NPIX + (size_t)(y0 + r) * 512 + x4);
            float4 bb = *(const float4*)(Iy + ((size_t)(b * 3) + 2) * NPIX + (size_t)(y0 + r) * 512 + x4);
            v = make_float4(fmaxf(g.x, bb.x), fmaxf(g.y, bb.y), fmaxf(g.z, bb.z), fmaxf(g.w, bb.w));
        }
        *(float4*)(&rowbuf[r][x4]) = v;
    }
    __syncthreads();

    // --- scans: 272 threads, each one 31-elem prefix or suffix scan ---
    if (tid < 272) {
        int type = tid / 136;
        int rem = tid % 136;
        int r = rem / 17;
        int seg = rem % 17;
        int s0 = seg * 31;
        if (type == 0) {                       // prefix
            float run = rowbuf[r][s0];
            PB[r][s0] = run;
            for (int j = 1; j < 31; ++j) {
                int idx = s0 + j;
                if (idx < 512) { run = fmaxf(run, rowbuf[r][idx]); PB[r][idx] = run; }
            }
        } else {                               // suffix
            int s1 = min(s0 + 30, 511);
            float run = rowbuf[r][s1];
            SB[r][s1] = run;
            for (int j = s1 - 1; j >= s0; --j) { run = fmaxf(run, rowbuf[r][j]); SB[r][j] = run; }
        }
    }
    __syncthreads();

    // --- combine + coalesced store ---
    int x = tid, a = x - 15, bc = x + 15;
#pragma unroll
    for (int r = 0; r < 8; ++r) {
        float o;
        if (a < 0)        o = PB[r][bc];
        else if (bc > 511) o = fmaxf(SB[r][a], PB[r][511]);
        else              o = fmaxf(SB[r][a], PB[r][bc]);
        H[(size_t)plane * NPIX + (size_t)(y0 + r) * 512 + x] = o;
    }
}

// vertical 31-max on BOTH planes (R and M) + combine into xb = |vR - vM| + R.
// grid: (8 x-tiles, 9 y-chunks [2 segs each], 16 batches), block 64.
__global__ __launch_bounds__(64) void vpassC_k(const float* __restrict__ H,
                                               const float* __restrict__ Iy,
                                               float* __restrict__ xb) {
    int x = blockIdx.x * 64 + threadIdx.x;
    int b = blockIdx.z;
    const float* inR = H + (size_t)b * NPIX;
    const float* inM = H + (size_t)(16 + b) * NPIX;
    const float* IyR = Iy + (size_t)(b * 3) * NPIX;
    float*       out = xb + (size_t)b * NPIX;
    int c0 = blockIdx.y * 2;

    float SprevR[31], SprevM[31];
    if (c0 > 0) {
        int s0 = (c0 - 1) * 31;
        float vR[31], vM[31];
#pragma unroll
        for (int j = 0; j < 31; ++j) {
            vR[j] = inR[(size_t)(s0 + j) * 512 + x];
            vM[j] = inM[(size_t)(s0 + j) * 512 + x];
        }
        float aR = NEGINF, aM = NEGINF;
#pragma unroll
        for (int j = 30; j >= 0; --j) {
            aR = fmaxf(aR, vR[j]); SprevR[j] = aR;
            aM = fmaxf(aM, vM[j]); SprevM[j] = aM;
        }
    } else {
#pragma unroll
        for (int j = 0; j < 31; ++j) { SprevR[j] = NEGINF; SprevM[j] = NEGINF; }
    }

    int send = min(c0 + 1, 16);
    for (int s = c0; s <= send; ++s) {
        int s0 = s * 31;
        float vR[31], vM[31];
#pragma unroll
        for (int j = 0; j < 31; ++j) {
            bool ok = (s0 + j < 512);
            vR[j] = ok ? inR[(size_t)(s0 + j) * 512 + x] : NEGINF;
            vM[j] = ok ? inM[(size_t)(s0 + j) * 512 + x] : NEGINF;
        }
        float ScurR[31], ScurM[31];
        float aR = NEGINF, aM = NEGINF;
#pragma unroll
        for (int j = 30; j >= 0; --j) {
            aR = fmaxf(aR, vR[j]); ScurR[j] = aR;
            aM = fmaxf(aM, vM[j]); ScurM[j] = aM;
        }
        float PR = NEGINF, PM = NEGINF;
#pragma unroll
        for (int r = 0; r < 31; ++r) {
            PR = fmaxf(PR, vR[r]);
            PM = fmaxf(PM, vM[r]);
            int i = s0 + r - 15;
            if (i >= 0 && i <= 511) {
                int a = s0 - 30 + r;
                float oR, oM;
                if (a < 0) { oR = PR; oM = PM; }
                else {
                    float SvR = (r == 30) ? ScurR[0] : SprevR[r + 1];
                    float SvM = (r == 30) ? ScurM[0] : SprevM[r + 1];
                    oR = fmaxf(SvR, PR);
                    oM = fmaxf(SvM, PM);
                }
                out[(size_t)i * 512 + x] = fabsf(oR - oM) + IyR[(size_t)i * 512 + x];
            }
        }
#pragma unroll
        for (int j = 0; j < 31; ++j) { SprevR[j] = ScurR[j]; SprevM[j] = ScurM[j]; }
    }
}

// ================= HISTOGRAM / QUANTILE =================

__global__ __launch_bounds__(1024) void zeroi_k(int* __restrict__ p) {
    p[blockIdx.x * 1024 + threadIdx.x] = 0;
}

__global__ __launch_bounds__(1024) void hist2_k(const float* __restrict__ v,
                                                int* __restrict__ hist) {
    __shared__ int lh[NBINS];
    int s = blockIdx.x, b = blockIdx.y, tid = threadIdx.x;
    for (int i = tid; i < NBINS; i += 1024) lh[i] = 0;
    __syncthreads();
    const float* p = v + (size_t)b * NPIX + (size_t)s * (NPIX / HSUB);
    for (int i = tid; i < NPIX / HSUB; i += 1024) {
        int bin = (int)(p[i] * (NBINS * 0.5f));
        bin = min(max(bin, 0), NBINS - 1);
        atomicAdd(&lh[bin], 1);
    }
    __syncthreads();
    for (int i = tid; i < NBINS; i += 1024) {
        int c = lh[i];
        if (c) atomicAdd(&hist[b * NBINS + i], c);
    }
}

__global__ __launch_bounds__(1024) void gradhisth_k(const __half* __restrict__ nh,
                                                    int* __restrict__ hist) {
    __shared__ int lh[NBINS];
    int s = blockIdx.x, b = blockIdx.y, tid = threadIdx.x;
    for (int i = tid; i < NBINS; i += 1024) lh[i] = 0;
    __syncthreads();
    const __half* p = nh + (size_t)b * NPIX;
    int base = s * (NPIX / HSUB);
    for (int ii = tid; ii < NPIX / HSUB; ii += 1024) {
        int i = base + ii;
        float c = __half2float(p[i]);
        int x = i & 511, y = i >> 9;
        float dx = (x < 511) ? __half2float(p[i + 1])   - c : 0.f;
        float dy = (y < 511) ? __half2float(p[i + 512]) - c : 0.f;
        float gm = sqrtf(dx * dx + dy * dy + EPSC);
        int bin = (int)(gm * (NBINS * 0.5f));
        bin = min(max(bin, 0), NBINS - 1);
        atomicAdd(&lh[bin], 1);
    }
    __syncthreads();
    for (int i = tid; i < NBINS; i += 1024) {
        int c = lh[i];
        if (c) atomicAdd(&hist[b * NBINS + i], c);
    }
}

__global__ __launch_bounds__(1024) void quant_k(const int* __restrict__ hist,
                                                float* __restrict__ scal,
                                                float q0, float q1, int s0, int s1) {
    __shared__ int csum[1025];
    int b = blockIdx.x, tid = threadIdx.x;
    const int* h = hist + b * NBINS;
    int s = 0;
#pragma unroll
    for (int j = 0; j < NBINS / 1024; ++j) s += h[tid * (NBINS / 1024) + j];
    csum[tid] = s;
    __syncthreads();
    if (tid == 0) {
        int acc = 0;
        for (int i = 0; i < 1024; ++i) { int v = csum[i]; csum[i] = acc; acc += v; }
        csum[1024] = acc;
    }
    __syncthreads();
    if (tid < 2) {
        int slot = tid ? s1 : s0;
        if (slot >= 0) {
            float q = tid ? q1 : q0;
            float t = q * (float)(NPIX - 1);
            int chunk = 1023;
            for (int i = 0; i < 1024; ++i) {
                if ((float)csum[i + 1] > t) { chunk = i; break; }
            }
            int per = NBINS / 1024;
            int cb = csum[chunk];
            int bin = chunk * per;
            int hv = 1;
            for (int j = 0; j < per; ++j) {
                hv = h[chunk * per + j];
                if ((float)(cb + hv) > t) { bin = chunk * per + j; break; }
                cb += hv;
            }
            float k = t - (float)cb;
            float val = ((float)bin + (k + 0.5f) / (float)hv) * (2.0f / NBINS);
            scal[b * 4 + slot] = val;
        }
    }
}

// ---------------- N_hat (fp16) from xb (fp32) ----------------
__global__ __launch_bounds__(256) void nhat2h_k(const float* __restrict__ xb,
                                                const float* __restrict__ scal,
                                                __half* __restrict__ nhh) {
    size_t i = ((size_t)blockIdx.x * 256 + threadIdx.x) * 4;
    int b = (int)(i >> 18);
    float lo = scal[b * 4 + 0], hi = scal[b * 4 + 1];
    float inv = 1.0f / (hi - lo + EPSC);
    float4 v = *(const float4*)(xb + i);
    float a0 = fminf(fmaxf((v.x - lo) * inv, 0.f), 1.f);
    float a1 = fminf(fmaxf((v.y - lo) * inv, 0.f), 1.f);
    float a2 = fminf(fmaxf((v.z - lo) * inv, 0.f), 1.f);
    float a3 = fminf(fmaxf((v.w - lo) * inv, 0.f), 1.f);
    *(__half2*)(nhh + i)     = __floats2half2_rn(a0, a1);
    *(__half2*)(nhh + i + 2) = __floats2half2_rn(a2, a3);
}

// ---------------- fused PD iteration, fp16 state, bounds recomputed ----------------
__global__ __launch_bounds__(256) void pdfh3_k(const __half* __restrict__ u,
                                               const __half* __restrict__ up,
                                               const __half* __restrict__ pxO,
                                               const __half* __restrict__ pyO,
                                               __half* __restrict__ pxN,
                                               __half* __restrict__ pyN,
                                               const __half* __restrict__ nh,
                                               const float* __restrict__ scal,
                                               __half* __restrict__ un,
                                               float* __restrict__ outF,
                                               int last) {
    int x0 = (blockIdx.x * 64 + threadIdx.x) * 4;
    int y  = blockIdx.y * 4 + threadIdx.y;
    int b  = blockIdx.z;
    size_t base = (size_t)b * NPIX + (size_t)y * 512 + x0;
    bool hasD = (y < 511), hasU = (y > 0);

    float uc[4], upc[4], ud[4] = {0,0,0,0}, upd[4] = {0,0,0,0}, uu[4] = {0,0,0,0}, upu[4] = {0,0,0,0};
    ld4h(u + base, uc); ld4h(up + base, upc);
    if (hasD) { ld4h(u + base + 512, ud); ld4h(up + base + 512, upd); }
    if (hasU) { ld4h(u + base - 512, uu); ld4h(up + base - 512, upu); }
    float bl = 0.f, br = 0.f;
    if (x0 > 0)   bl = 2.f * __half2float(u[base - 1]) - __half2float(up[base - 1]);
    if (x0 < 508) br = 2.f * __half2float(u[base + 4]) - __half2float(up[base + 4]);

    float bc[4], bd[4], bu[4];
#pragma unroll
    for (int i = 0; i < 4; ++i) {
        bc[i] = 2.f * uc[i] - upc[i];
        bd[i] = 2.f * ud[i] - upd[i];
        bu[i] = 2.f * uu[i] - upu[i];
    }

    // N_hat neighborhood for bound recompute + u-update
    float nhc[4]; ld4h(nh + base, nhc);
    float nhR = (x0 < 508) ? __half2float(nh[base + 4]) : 0.f;
    float nhL = (x0 > 0)   ? __half2float(nh[base - 1]) : 0.f;
    float nhD[4] = {0,0,0,0}, nhU[4] = {0,0,0,0};
    if (hasD) ld4h(nh + base + 512, nhD);
    if (hasU) ld4h(nh + base - 512, nhU);
    float sgm = fmaxf(scal[b * 4 + 2], EPSC);
    float inv = 1.0f / sgm;

    float bxc[4], byc[4], byu[4];
#pragma unroll
    for (int i = 0; i < 4; ++i) {
        float dxn = (x0 + i < 511) ? ((i < 3 ? nhc[i + 1] : nhR) - nhc[i]) : 0.f;
        bxc[i] = bnd(dxn, inv);
        float dyn = hasD ? (nhD[i] - nhc[i]) : 0.f;
        byc[i] = bnd(dyn, inv);
        byu[i] = bnd(nhc[i] - nhU[i], inv);   // valid only when hasU (guarded below)
    }

    float pxc[4], pyc[4], pyu[4] = {0,0,0,0};
    ld4h(pxO + base, pxc);
    ld4h(pyO + base, pyc);
    if (hasU) ld4h(pyO + base - 512, pyu);

    float pxm1 = 0.f;
    if (x0 > 0) {
        float pxl = __half2float(pxO[base - 1]);
        float bxl = bnd(nhc[0] - nhL, inv);
        pxm1 = __half2float(__float2half_rn(fminf(fmaxf(pxl + SIG * (bc[0] - bl), -bxl), bxl)));
    }

    float pxn[4], pyn[4], pynU[4];
    __half pxh[4], pyh[4];
#pragma unroll
    for (int i = 0; i < 4; ++i) {
        float right = (i < 3) ? bc[i + 1] : br;
        float dx = (x0 + i < 511) ? right - bc[i] : 0.f;
        __half h = __float2half_rn(fminf(fmaxf(pxc[i] + SIG * dx, -bxc[i]), bxc[i]));
        pxh[i] = h; pxn[i] = __half2float(h);
        float dy = hasD ? bd[i] - bc[i] : 0.f;
        __half h2 = __float2half_rn(fminf(fmaxf(pyc[i] + SIG * dy, -byc[i]), byc[i]));
        pyh[i] = h2; pyn[i] = __half2float(h2);
        float dyU = bc[i] - bu[i];
        pynU[i] = __half2float(__float2half_rn(fminf(fmaxf(pyu[i] + SIG * dyU, -byu[i]), byu[i])));
    }

    if (!last) {
        *(__half2*)(pxN + base)     = __half2(pxh[0], pxh[1]);
        *(__half2*)(pxN + base + 2) = __half2(pxh[2], pxh[3]);
        *(__half2*)(pyN + base)     = __half2(pyh[0], pyh[1]);
        *(__half2*)(pyN + base + 2) = __half2(pyh[2], pyh[3]);
    }

    float unew[4];
#pragma unroll
    for (int i = 0; i < 4; ++i) {
        float left = (i > 0) ? pxn[i - 1] : pxm1;
        float div = pxn[i] + pyn[i] - left - (hasU ? pynU[i] : 0.f);
        unew[i] = (uc[i] + TAUC * div + TAUC * nhc[i]) * (1.0f / (1.0f + TAUC));
    }
    if (last) {
        float4 o;
        o.x = fminf(fmaxf(unew[0], 0.f), 1.f);
        o.y = fminf(fmaxf(unew[1], 0.f), 1.f);
        o.z = fminf(fmaxf(unew[2], 0.f), 1.f);
        o.w = fminf(fmaxf(unew[3], 0.f), 1.f);
        *(float4*)(outF + base) = o;
    } else {
        *(__half2*)(un + base)     = __floats2half2_rn(unew[0], unew[1]);
        *(__half2*)(un + base + 2) = __floats2half2_rn(unew[2], unew[3]);
    }
}

extern "C" void kernel_launch(void* const* d_in, const int* in_sizes, int n_in,
                              void* d_out, int out_size, void* d_ws, size_t ws_size,
                              hipStream_t stream) {
    const float* Iy = (const float*)d_in[0];
    float* ws = (float*)d_ws;
    float* out = (float*)d_out;

    dim3 f4_g(2, 128, 16), tile_b(64, 4);
    dim3 hist_g(HSUB, 16);

    // layout (float units):
    // 0..NP: xb (fp32) | NP..3NP: H (2 planes fp32) | 3NP..7NP: fp16 arrays (8*NP halfs) | 7NP: hist,scal
    float*  xb = ws;
    float*  H  = ws + (size_t)NP;
    __half* hb = (__half*)(ws + (size_t)3 * NP);
    __half* nhh = hb;
    __half* HA  = hb + (size_t)NP;
    __half* HB  = hb + (size_t)2 * NP;
    __half* HC  = hb + (size_t)3 * NP;
    __half* pxA = hb + (size_t)4 * NP;
    __half* pyA = hb + (size_t)5 * NP;
    __half* pxB = hb + (size_t)6 * NP;
    __half* pyB = hb + (size_t)7 * NP;
    int*    hist = (int*)(ws + (size_t)7 * NP);
    float*  scal = ws + (size_t)7 * NP + 16 * NBINS;

    // 1. separable 31x31 max pool (R and M=max(G,B)) fused with Dmip combine
    hpass3_k<<<dim3(64, 32), dim3(512), 0, stream>>>(Iy, H);
    vpassC_k<<<dim3(8, 9, 16), dim3(64), 0, stream>>>(H, Iy, xb);

    // 2. robust normalize -> fp16 N_hat
    zeroi_k<<<16 * NBINS / 1024, 1024, 0, stream>>>(hist);
    hist2_k<<<hist_g, 1024, 0, stream>>>(xb, hist);
    quant_k<<<16, 1024, 0, stream>>>(hist, scal, 0.01f, 0.99f, 0, 1);
    nhat2h_k<<<NP / 1024, 256, 0, stream>>>(xb, scal, nhh);

    // 3. sigma (median grad mag); zero fp16 p (pxA,pyA contiguous)
    zeroi_k<<<16 * NBINS / 1024, 1024, 0, stream>>>(hist);
    gradhisth_k<<<hist_g, 1024, 0, stream>>>(nhh, hist);
    quant_k<<<16, 1024, 0, stream>>>(hist, scal, 0.5f, 0.5f, 2, -1);
    hipMemsetAsync(pxA, 0, (size_t)2 * NP * sizeof(__half), stream);

    // 4. 30 fused PD iterations (u_bar = 2u - u_prev), fp16 state, recomputed bounds
    const __half* ucur = nhh;
    const __half* uprev = nhh;
    __half* Ubuf[3] = {HA, HB, HC};
    __half* pxs[2] = {pxA, pxB};
    __half* pys[2] = {pyA, pyB};
    for (int t = 0; t < 30; ++t) {
        __half* un = Ubuf[t % 3];
        int cur = t & 1;
        pdfh3_k<<<f4_g, tile_b, 0, stream>>>(ucur, uprev,
                                             pxs[cur], pys[cur],
                                             pxs[cur ^ 1], pys[cur ^ 1],
                                             nhh, scal, un, out, (t == 29) ? 1 : 0);
        uprev = ucur;
        ucur = un;
    }
    // t=29 wrote clipped fp32 result directly to out.
}

// Round 6
// 690.108 us; speedup vs baseline: 2.4708x; 1.0761x over previous
//
#include <hip/hip_runtime.h>
#include <hip/hip_bf16.h>
#include <hip/hip_fp16.h>
#include <math.h>

#define NPIX   262144          // 512*512
#define NP     4194304         // 16*512*512
#define NBINS  8192
#define HSUB   16
#define SIG    0.125f
#define TAUC   0.125f
#define ALPHAC 0.15f
#define MUC    10.0f
#define EPSC   1e-6f
#define NEGINF -3.4e38f

// ---------- helpers ----------
__device__ __forceinline__ void ld8h(const __half* p, float* d) {
    float4 raw = *(const float4*)p;               // one dwordx4
    const __half2* h = (const __half2*)&raw;
#pragma unroll
    for (int j = 0; j < 4; ++j) {
        float2 f = __half22float2(h[j]);
        d[2 * j] = f.x; d[2 * j + 1] = f.y;
    }
}
__device__ __forceinline__ float bnd(float d, float inv) {
    return ALPHAC * (1.f + MUC * __expf(-fabsf(d) * inv));
}

// ================= POOLING =================

// horizontal 31-max, 3-phase vHGW: coalesced stage -> parallel register scans -> combine.
__global__ __launch_bounds__(512) void hpass3_k(const float* __restrict__ Iy,
                                                float* __restrict__ H) {
    __shared__ float rowbuf[8][512];
    __shared__ float PB[8][512];
    __shared__ float SB[8][512];
    int tid = threadIdx.x;
    int plane = blockIdx.y;
    int y0 = blockIdx.x * 8;

#pragma unroll
    for (int q = 0; q < 2; ++q) {
        int idx = q * 512 + tid;
        int r = idx >> 7;
        int x4 = (idx & 127) << 2;
        float4 v;
        if (plane < 16) {
            v = *(const float4*)(Iy + (size_t)(plane * 3) * NPIX + (size_t)(y0 + r) * 512 + x4);
        } else {
            int b = plane - 16;
            float4 g = *(const float4*)(Iy + ((size_t)(b * 3) + 1) * NPIX + (size_t)(y0 + r) * 512 + x4);
            float4 bb = *(const float4*)(Iy + ((size_t)(b * 3) + 2) * NPIX + (size_t)(y0 + r) * 512 + x4);
            v = make_float4(fmaxf(g.x, bb.x), fmaxf(g.y, bb.y), fmaxf(g.z, bb.z), fmaxf(g.w, bb.w));
        }
        *(float4*)(&rowbuf[r][x4]) = v;
    }
    __syncthreads();

    if (tid < 272) {
        int type = tid / 136;
        int rem = tid % 136;
        int r = rem / 17;
        int seg = rem % 17;
        int s0 = seg * 31;
        if (type == 0) {
            float run = rowbuf[r][s0];
            PB[r][s0] = run;
            for (int j = 1; j < 31; ++j) {
                int idx = s0 + j;
                if (idx < 512) { run = fmaxf(run, rowbuf[r][idx]); PB[r][idx] = run; }
            }
        } else {
            int s1 = min(s0 + 30, 511);
            float run = rowbuf[r][s1];
            SB[r][s1] = run;
            for (int j = s1 - 1; j >= s0; --j) { run = fmaxf(run, rowbuf[r][j]); SB[r][j] = run; }
        }
    }
    __syncthreads();

    int x = tid, a = x - 15, bc = x + 15;
#pragma unroll
    for (int r = 0; r < 8; ++r) {
        float o;
        if (a < 0)        o = PB[r][bc];
        else if (bc > 511) o = fmaxf(SB[r][a], PB[r][511]);
        else              o = fmaxf(SB[r][a], PB[r][bc]);
        H[(size_t)plane * NPIX + (size_t)(y0 + r) * 512 + x] = o;
    }
}

// vertical 31-max on BOTH planes + combine into xb = |vR - vM| + R.
__global__ __launch_bounds__(64) void vpassC_k(const float* __restrict__ H,
                                               const float* __restrict__ Iy,
                                               float* __restrict__ xb) {
    int x = blockIdx.x * 64 + threadIdx.x;
    int b = blockIdx.z;
    const float* inR = H + (size_t)b * NPIX;
    const float* inM = H + (size_t)(16 + b) * NPIX;
    const float* IyR = Iy + (size_t)(b * 3) * NPIX;
    float*       out = xb + (size_t)b * NPIX;
    int c0 = blockIdx.y * 2;

    float SprevR[31], SprevM[31];
    if (c0 > 0) {
        int s0 = (c0 - 1) * 31;
        float vR[31], vM[31];
#pragma unroll
        for (int j = 0; j < 31; ++j) {
            vR[j] = inR[(size_t)(s0 + j) * 512 + x];
            vM[j] = inM[(size_t)(s0 + j) * 512 + x];
        }
        float aR = NEGINF, aM = NEGINF;
#pragma unroll
        for (int j = 30; j >= 0; --j) {
            aR = fmaxf(aR, vR[j]); SprevR[j] = aR;
            aM = fmaxf(aM, vM[j]); SprevM[j] = aM;
        }
    } else {
#pragma unroll
        for (int j = 0; j < 31; ++j) { SprevR[j] = NEGINF; SprevM[j] = NEGINF; }
    }

    int send = min(c0 + 1, 16);
    for (int s = c0; s <= send; ++s) {
        int s0 = s * 31;
        float vR[31], vM[31];
#pragma unroll
        for (int j = 0; j < 31; ++j) {
            bool ok = (s0 + j < 512);
            vR[j] = ok ? inR[(size_t)(s0 + j) * 512 + x] : NEGINF;
            vM[j] = ok ? inM[(size_t)(s0 + j) * 512 + x] : NEGINF;
        }
        float ScurR[31], ScurM[31];
        float aR = NEGINF, aM = NEGINF;
#pragma unroll
        for (int j = 30; j >= 0; --j) {
            aR = fmaxf(aR, vR[j]); ScurR[j] = aR;
            aM = fmaxf(aM, vM[j]); ScurM[j] = aM;
        }
        float PR = NEGINF, PM = NEGINF;
#pragma unroll
        for (int r = 0; r < 31; ++r) {
            PR = fmaxf(PR, vR[r]);
            PM = fmaxf(PM, vM[r]);
            int i = s0 + r - 15;
            if (i >= 0 && i <= 511) {
                int a = s0 - 30 + r;
                float oR, oM;
                if (a < 0) { oR = PR; oM = PM; }
                else {
                    float SvR = (r == 30) ? ScurR[0] : SprevR[r + 1];
                    float SvM = (r == 30) ? ScurM[0] : SprevM[r + 1];
                    oR = fmaxf(SvR, PR);
                    oM = fmaxf(SvM, PM);
                }
                out[(size_t)i * 512 + x] = fabsf(oR - oM) + IyR[(size_t)i * 512 + x];
            }
        }
#pragma unroll
        for (int j = 0; j < 31; ++j) { SprevR[j] = ScurR[j]; SprevM[j] = ScurM[j]; }
    }
}

// ================= HISTOGRAM / QUANTILE =================

__global__ __launch_bounds__(1024) void zeroi_k(int* __restrict__ p) {
    p[blockIdx.x * 1024 + threadIdx.x] = 0;
}

__global__ __launch_bounds__(1024) void hist2_k(const float* __restrict__ v,
                                                int* __restrict__ hist) {
    __shared__ int lh[NBINS];
    int s = blockIdx.x, b = blockIdx.y, tid = threadIdx.x;
    for (int i = tid; i < NBINS; i += 1024) lh[i] = 0;
    __syncthreads();
    const float* p = v + (size_t)b * NPIX + (size_t)s * (NPIX / HSUB);
    for (int i = tid; i < NPIX / HSUB; i += 1024) {
        int bin = (int)(p[i] * (NBINS * 0.5f));
        bin = min(max(bin, 0), NBINS - 1);
        atomicAdd(&lh[bin], 1);
    }
    __syncthreads();
    for (int i = tid; i < NBINS; i += 1024) {
        int c = lh[i];
        if (c) atomicAdd(&hist[b * NBINS + i], c);
    }
}

__global__ __launch_bounds__(1024) void gradhisth_k(const __half* __restrict__ nh,
                                                    int* __restrict__ hist) {
    __shared__ int lh[NBINS];
    int s = blockIdx.x, b = blockIdx.y, tid = threadIdx.x;
    for (int i = tid; i < NBINS; i += 1024) lh[i] = 0;
    __syncthreads();
    const __half* p = nh + (size_t)b * NPIX;
    int base = s * (NPIX / HSUB);
    for (int ii = tid; ii < NPIX / HSUB; ii += 1024) {
        int i = base + ii;
        float c = __half2float(p[i]);
        int x = i & 511, y = i >> 9;
        float dx = (x < 511) ? __half2float(p[i + 1])   - c : 0.f;
        float dy = (y < 511) ? __half2float(p[i + 512]) - c : 0.f;
        float gm = sqrtf(dx * dx + dy * dy + EPSC);
        int bin = (int)(gm * (NBINS * 0.5f));
        bin = min(max(bin, 0), NBINS - 1);
        atomicAdd(&lh[bin], 1);
    }
    __syncthreads();
    for (int i = tid; i < NBINS; i += 1024) {
        int c = lh[i];
        if (c) atomicAdd(&hist[b * NBINS + i], c);
    }
}

// parallel-scan quantile: wave shfl scan + 16-wave combine + parallel bracket find
__global__ __launch_bounds__(1024) void quant2_k(const int* __restrict__ hist,
                                                 float* __restrict__ scal,
                                                 float q0, float q1, int s0, int s1) {
    __shared__ int csum[1025];
    __shared__ int wsum[16];
    int b = blockIdx.x, tid = threadIdx.x;
    const int* h = hist + b * NBINS;
    int s = 0;
#pragma unroll
    for (int j = 0; j < NBINS / 1024; ++j) s += h[tid * (NBINS / 1024) + j];

    int lane = tid & 63, wave = tid >> 6;
    int v = s;
#pragma unroll
    for (int off = 1; off < 64; off <<= 1) {
        int n = __shfl_up(v, off, 64);
        if (lane >= off) v += n;
    }
    if (lane == 63) wsum[wave] = v;
    __syncthreads();
    if (wave == 0 && lane < 16) {
        int w = wsum[lane];
#pragma unroll
        for (int off = 1; off < 16; off <<= 1) {
            int n = __shfl_up(w, off, 64);
            if (lane >= off) w += n;
        }
        wsum[lane] = w;   // inclusive wave sums
    }
    __syncthreads();
    int incl = v + (wave > 0 ? wsum[wave - 1] : 0);
    csum[tid + 1] = incl;
    if (tid == 0) csum[0] = 0;
    __syncthreads();

#pragma unroll
    for (int pass = 0; pass < 2; ++pass) {
        int slot = pass ? s1 : s0;
        if (slot < 0) continue;
        float q = pass ? q1 : q0;
        float t = q * (float)(NPIX - 1);
        if ((float)csum[tid] <= t && (float)csum[tid + 1] > t) {
            const int per = NBINS / 1024;
            int cb = csum[tid];
            int bin = tid * per;
            int hv = 1;
            for (int j = 0; j < per; ++j) {
                hv = h[tid * per + j];
                if ((float)(cb + hv) > t) { bin = tid * per + j; break; }
                cb += hv;
            }
            float k = t - (float)cb;
            scal[b * 4 + slot] = ((float)bin + (k + 0.5f) / (float)hv) * (2.0f / NBINS);
        }
    }
}

// ---------------- N_hat (fp16) from xb (fp32) ----------------
__global__ __launch_bounds__(256) void nhat2h_k(const float* __restrict__ xb,
                                                const float* __restrict__ scal,
                                                __half* __restrict__ nhh) {
    size_t i = ((size_t)blockIdx.x * 256 + threadIdx.x) * 4;
    int b = (int)(i >> 18);
    float lo = scal[b * 4 + 0], hi = scal[b * 4 + 1];
    float inv = 1.0f / (hi - lo + EPSC);
    float4 v = *(const float4*)(xb + i);
    float a0 = fminf(fmaxf((v.x - lo) * inv, 0.f), 1.f);
    float a1 = fminf(fmaxf((v.y - lo) * inv, 0.f), 1.f);
    float a2 = fminf(fmaxf((v.z - lo) * inv, 0.f), 1.f);
    float a3 = fminf(fmaxf((v.w - lo) * inv, 0.f), 1.f);
    *(__half2*)(nhh + i)     = __floats2half2_rn(a0, a1);
    *(__half2*)(nhh + i + 2) = __floats2half2_rn(a2, a3);
}

// ---------------- fused PD iteration, fp16 state, 8 px/thread ----------------
__global__ __launch_bounds__(256) void pdfh4_k(const __half* __restrict__ u,
                                               const __half* __restrict__ up,
                                               const __half* __restrict__ pxO,
                                               const __half* __restrict__ pyO,
                                               __half* __restrict__ pxN,
                                               __half* __restrict__ pyN,
                                               const __half* __restrict__ nh,
                                               const float* __restrict__ scal,
                                               __half* __restrict__ un,
                                               float* __restrict__ outF,
                                               int last) {
    int x0 = threadIdx.x * 8;                 // 64 threads cover 512
    int y  = blockIdx.y * 4 + threadIdx.y;
    int b  = blockIdx.z;
    size_t base = (size_t)b * NPIX + (size_t)y * 512 + x0;
    bool hasD = (y < 511), hasU = (y > 0);
    bool hasL = (x0 > 0), hasR = (x0 < 504);

    float uc[8], upc[8];
    ld8h(u + base, uc); ld8h(up + base, upc);
    float bc[8];
#pragma unroll
    for (int i = 0; i < 8; ++i) bc[i] = 2.f * uc[i] - upc[i];

    float bd[8] = {0,0,0,0,0,0,0,0}, bu[8] = {0,0,0,0,0,0,0,0};
    if (hasD) {
        float t[8], s2[8];
        ld8h(u + base + 512, t); ld8h(up + base + 512, s2);
#pragma unroll
        for (int i = 0; i < 8; ++i) bd[i] = 2.f * t[i] - s2[i];
    }
    if (hasU) {
        float t[8], s2[8];
        ld8h(u + base - 512, t); ld8h(up + base - 512, s2);
#pragma unroll
        for (int i = 0; i < 8; ++i) bu[i] = 2.f * t[i] - s2[i];
    }
    float bl = 0.f, br = 0.f;
    if (hasL) bl = 2.f * __half2float(u[base - 1]) - __half2float(up[base - 1]);
    if (hasR) br = 2.f * __half2float(u[base + 8]) - __half2float(up[base + 8]);

    float nhc[8]; ld8h(nh + base, nhc);
    float nhD[8] = {0,0,0,0,0,0,0,0}, nhU[8] = {0,0,0,0,0,0,0,0};
    if (hasD) ld8h(nh + base + 512, nhD);
    if (hasU) ld8h(nh + base - 512, nhU);
    float nhR = hasR ? __half2float(nh[base + 8]) : 0.f;
    float nhL = hasL ? __half2float(nh[base - 1]) : 0.f;
    float sgm = fmaxf(scal[b * 4 + 2], EPSC);
    float inv = 1.0f / sgm;

    float pxc[8], pyc[8], pyu[8] = {0,0,0,0,0,0,0,0};
    ld8h(pxO + base, pxc);
    ld8h(pyO + base, pyc);
    if (hasU) ld8h(pyO + base - 512, pyu);

    float pxm1 = 0.f;
    if (hasL) {
        float pxl = __half2float(pxO[base - 1]);
        float bxl = bnd(nhc[0] - nhL, inv);
        pxm1 = __half2float(__float2half_rn(fminf(fmaxf(pxl + SIG * (bc[0] - bl), -bxl), bxl)));
    }

    float pxn[8], pyn[8], pynU[8];
    __half2 pxh[4], pyh[4];
#pragma unroll
    for (int i = 0; i < 8; ++i) {
        float nright = (i < 7) ? nhc[i + 1] : nhR;
        float dxn = (x0 + i < 511) ? (nright - nhc[i]) : 0.f;
        float bxc = bnd(dxn, inv);
        float byc = bnd(hasD ? (nhD[i] - nhc[i]) : 0.f, inv);
        float byu = bnd(nhc[i] - nhU[i], inv);

        float right = (i < 7) ? bc[i + 1] : br;
        float dx = (x0 + i < 511) ? right - bc[i] : 0.f;
        __half h = __float2half_rn(fminf(fmaxf(pxc[i] + SIG * dx, -bxc), bxc));
        pxn[i] = __half2float(h);
        float dy = hasD ? bd[i] - bc[i] : 0.f;
        __half h2 = __float2half_rn(fminf(fmaxf(pyc[i] + SIG * dy, -byc), byc));
        pyn[i] = __half2float(h2);
        float dyU = bc[i] - bu[i];
        pynU[i] = __half2float(__float2half_rn(fminf(fmaxf(pyu[i] + SIG * dyU, -byu), byu)));
        if (i & 1) {
            pxh[i >> 1] = __half2(__float2half_rn(pxn[i - 1]), h);
            pyh[i >> 1] = __half2(__float2half_rn(pyn[i - 1]), h2);
        }
    }

    if (!last) {
        float4 vx, vy;
        __half2* hx = (__half2*)&vx; __half2* hy = (__half2*)&vy;
#pragma unroll
        for (int j = 0; j < 4; ++j) { hx[j] = pxh[j]; hy[j] = pyh[j]; }
        *(float4*)(pxN + base) = vx;
        *(float4*)(pyN + base) = vy;
    }

    float unew[8];
#pragma unroll
    for (int i = 0; i < 8; ++i) {
        float left = (i > 0) ? pxn[i - 1] : pxm1;
        float div = pxn[i] + pyn[i] - left - (hasU ? pynU[i] : 0.f);
        unew[i] = (uc[i] + TAUC * div + TAUC * nhc[i]) * (1.0f / (1.0f + TAUC));
    }
    if (last) {
        float4 o0, o1;
        o0.x = fminf(fmaxf(unew[0], 0.f), 1.f);
        o0.y = fminf(fmaxf(unew[1], 0.f), 1.f);
        o0.z = fminf(fmaxf(unew[2], 0.f), 1.f);
        o0.w = fminf(fmaxf(unew[3], 0.f), 1.f);
        o1.x = fminf(fmaxf(unew[4], 0.f), 1.f);
        o1.y = fminf(fmaxf(unew[5], 0.f), 1.f);
        o1.z = fminf(fmaxf(unew[6], 0.f), 1.f);
        o1.w = fminf(fmaxf(unew[7], 0.f), 1.f);
        *(float4*)(outF + base)     = o0;
        *(float4*)(outF + base + 4) = o1;
    } else {
        float4 vu;
        __half2* hu = (__half2*)&vu;
#pragma unroll
        for (int j = 0; j < 4; ++j) hu[j] = __floats2half2_rn(unew[2 * j], unew[2 * j + 1]);
        *(float4*)(un + base) = vu;
    }
}

extern "C" void kernel_launch(void* const* d_in, const int* in_sizes, int n_in,
                              void* d_out, int out_size, void* d_ws, size_t ws_size,
                              hipStream_t stream) {
    const float* Iy = (const float*)d_in[0];
    float* ws = (float*)d_ws;
    float* out = (float*)d_out;

    dim3 f8_g(1, 128, 16), tile_b(64, 4);
    dim3 hist_g(HSUB, 16);

    float*  xb = ws;
    float*  H  = ws + (size_t)NP;
    __half* hb = (__half*)(ws + (size_t)3 * NP);
    __half* nhh = hb;
    __half* HA  = hb + (size_t)NP;
    __half* HB  = hb + (size_t)2 * NP;
    __half* HC  = hb + (size_t)3 * NP;
    __half* pxA = hb + (size_t)4 * NP;
    __half* pyA = hb + (size_t)5 * NP;
    __half* pxB = hb + (size_t)6 * NP;
    __half* pyB = hb + (size_t)7 * NP;
    int*    hist = (int*)(ws + (size_t)7 * NP);
    float*  scal = ws + (size_t)7 * NP + 16 * NBINS;

    // 1. separable 31x31 max pool (R and M=max(G,B)) fused with Dmip combine
    hpass3_k<<<dim3(64, 32), dim3(512), 0, stream>>>(Iy, H);
    vpassC_k<<<dim3(8, 9, 16), dim3(64), 0, stream>>>(H, Iy, xb);

    // 2. robust normalize -> fp16 N_hat
    zeroi_k<<<16 * NBINS / 1024, 1024, 0, stream>>>(hist);
    hist2_k<<<hist_g, 1024, 0, stream>>>(xb, hist);
    quant2_k<<<16, 1024, 0, stream>>>(hist, scal, 0.01f, 0.99f, 0, 1);
    nhat2h_k<<<NP / 1024, 256, 0, stream>>>(xb, scal, nhh);

    // 3. sigma (median grad mag); zero fp16 p (pxA,pyA contiguous)
    zeroi_k<<<16 * NBINS / 1024, 1024, 0, stream>>>(hist);
    gradhisth_k<<<hist_g, 1024, 0, stream>>>(nhh, hist);
    quant2_k<<<16, 1024, 0, stream>>>(hist, scal, 0.5f, 0.5f, 2, -1);
    hipMemsetAsync(pxA, 0, (size_t)2 * NP * sizeof(__half), stream);

    // 4. 30 fused PD iterations (u_bar = 2u - u_prev), fp16 state, recomputed bounds
    const __half* ucur = nhh;
    const __half* uprev = nhh;
    __half* Ubuf[3] = {HA, HB, HC};
    __half* pxs[2] = {pxA, pxB};
    __half* pys[2] = {pyA, pyB};
    for (int t = 0; t < 30; ++t) {
        __half* un = Ubuf[t % 3];
        int cur = t & 1;
        pdfh4_k<<<f8_g, tile_b, 0, stream>>>(ucur, uprev,
                                             pxs[cur], pys[cur],
                                             pxs[cur ^ 1], pys[cur ^ 1],
                                             nhh, scal, un, out, (t == 29) ? 1 : 0);
        uprev = ucur;
        ucur = un;
    }
    // t=29 wrote clipped fp32 result directly to out.
}

// Round 7
// 583.042 us; speedup vs baseline: 2.9245x; 1.1836x over previous
//
#include <hip/hip_runtime.h>
#include <hip/hip_bf16.h>
#include <hip/hip_fp16.h>
#include <math.h>

#define NPIX   262144          // 512*512
#define NP     4194304         // 16*512*512
#define NBINS  8192
#define HSUB   16
#define RSTRIP 4               // rows per thread in PD kernel
#define SIG    0.125f
#define TAUC   0.125f
#define ALPHAC 0.15f
#define MUC    10.0f
#define EPSC   1e-6f
#define NEGINF -3.4e38f

// ---------- helpers ----------
__device__ __forceinline__ void ld8h(const __half* p, float* d) {
    float4 raw = *(const float4*)p;               // one dwordx4
    const __half2* h = (const __half2*)&raw;
#pragma unroll
    for (int j = 0; j < 4; ++j) {
        float2 f = __half22float2(h[j]);
        d[2 * j] = f.x; d[2 * j + 1] = f.y;
    }
}
__device__ __forceinline__ float bnd(float d, float inv) {
    return ALPHAC * (1.f + MUC * __expf(-fabsf(d) * inv));
}
__device__ __forceinline__ float clmp(float v, float b) {
    return fminf(fmaxf(v, -b), b);
}

// ================= POOLING =================

__global__ __launch_bounds__(512) void hpass3_k(const float* __restrict__ Iy,
                                                float* __restrict__ H) {
    __shared__ float rowbuf[8][512];
    __shared__ float PB[8][512];
    __shared__ float SB[8][512];
    int tid = threadIdx.x;
    int plane = blockIdx.y;
    int y0 = blockIdx.x * 8;

#pragma unroll
    for (int q = 0; q < 2; ++q) {
        int idx = q * 512 + tid;
        int r = idx >> 7;
        int x4 = (idx & 127) << 2;
        float4 v;
        if (plane < 16) {
            v = *(const float4*)(Iy + (size_t)(plane * 3) * NPIX + (size_t)(y0 + r) * 512 + x4);
        } else {
            int b = plane - 16;
            float4 g = *(const float4*)(Iy + ((size_t)(b * 3) + 1) * NPIX + (size_t)(y0 + r) * 512 + x4);
            float4 bb = *(const float4*)(Iy + ((size_t)(b * 3) + 2) * NPIX + (size_t)(y0 + r) * 512 + x4);
            v = make_float4(fmaxf(g.x, bb.x), fmaxf(g.y, bb.y), fmaxf(g.z, bb.z), fmaxf(g.w, bb.w));
        }
        *(float4*)(&rowbuf[r][x4]) = v;
    }
    __syncthreads();

    if (tid < 272) {
        int type = tid / 136;
        int rem = tid % 136;
        int r = rem / 17;
        int seg = rem % 17;
        int s0 = seg * 31;
        if (type == 0) {
            float run = rowbuf[r][s0];
            PB[r][s0] = run;
            for (int j = 1; j < 31; ++j) {
                int idx = s0 + j;
                if (idx < 512) { run = fmaxf(run, rowbuf[r][idx]); PB[r][idx] = run; }
            }
        } else {
            int s1 = min(s0 + 30, 511);
            float run = rowbuf[r][s1];
            SB[r][s1] = run;
            for (int j = s1 - 1; j >= s0; --j) { run = fmaxf(run, rowbuf[r][j]); SB[r][j] = run; }
        }
    }
    __syncthreads();

    int x = tid, a = x - 15, bc = x + 15;
#pragma unroll
    for (int r = 0; r < 8; ++r) {
        float o;
        if (a < 0)        o = PB[r][bc];
        else if (bc > 511) o = fmaxf(SB[r][a], PB[r][511]);
        else              o = fmaxf(SB[r][a], PB[r][bc]);
        H[(size_t)plane * NPIX + (size_t)(y0 + r) * 512 + x] = o;
    }
}

__global__ __launch_bounds__(64) void vpassC_k(const float* __restrict__ H,
                                               const float* __restrict__ Iy,
                                               float* __restrict__ xb) {
    int x = blockIdx.x * 64 + threadIdx.x;
    int b = blockIdx.z;
    const float* inR = H + (size_t)b * NPIX;
    const float* inM = H + (size_t)(16 + b) * NPIX;
    const float* IyR = Iy + (size_t)(b * 3) * NPIX;
    float*       out = xb + (size_t)b * NPIX;
    int c0 = blockIdx.y * 2;

    float SprevR[31], SprevM[31];
    if (c0 > 0) {
        int s0 = (c0 - 1) * 31;
        float vR[31], vM[31];
#pragma unroll
        for (int j = 0; j < 31; ++j) {
            vR[j] = inR[(size_t)(s0 + j) * 512 + x];
            vM[j] = inM[(size_t)(s0 + j) * 512 + x];
        }
        float aR = NEGINF, aM = NEGINF;
#pragma unroll
        for (int j = 30; j >= 0; --j) {
            aR = fmaxf(aR, vR[j]); SprevR[j] = aR;
            aM = fmaxf(aM, vM[j]); SprevM[j] = aM;
        }
    } else {
#pragma unroll
        for (int j = 0; j < 31; ++j) { SprevR[j] = NEGINF; SprevM[j] = NEGINF; }
    }

    int send = min(c0 + 1, 16);
    for (int s = c0; s <= send; ++s) {
        int s0 = s * 31;
        float vR[31], vM[31];
#pragma unroll
        for (int j = 0; j < 31; ++j) {
            bool ok = (s0 + j < 512);
            vR[j] = ok ? inR[(size_t)(s0 + j) * 512 + x] : NEGINF;
            vM[j] = ok ? inM[(size_t)(s0 + j) * 512 + x] : NEGINF;
        }
        float ScurR[31], ScurM[31];
        float aR = NEGINF, aM = NEGINF;
#pragma unroll
        for (int j = 30; j >= 0; --j) {
            aR = fmaxf(aR, vR[j]); ScurR[j] = aR;
            aM = fmaxf(aM, vM[j]); ScurM[j] = aM;
        }
        float PR = NEGINF, PM = NEGINF;
#pragma unroll
        for (int r = 0; r < 31; ++r) {
            PR = fmaxf(PR, vR[r]);
            PM = fmaxf(PM, vM[r]);
            int i = s0 + r - 15;
            if (i >= 0 && i <= 511) {
                int a = s0 - 30 + r;
                float oR, oM;
                if (a < 0) { oR = PR; oM = PM; }
                else {
                    float SvR = (r == 30) ? ScurR[0] : SprevR[r + 1];
                    float SvM = (r == 30) ? ScurM[0] : SprevM[r + 1];
                    oR = fmaxf(SvR, PR);
                    oM = fmaxf(SvM, PM);
                }
                out[(size_t)i * 512 + x] = fabsf(oR - oM) + IyR[(size_t)i * 512 + x];
            }
        }
#pragma unroll
        for (int j = 0; j < 31; ++j) { SprevR[j] = ScurR[j]; SprevM[j] = ScurM[j]; }
    }
}

// ================= HISTOGRAM / QUANTILE =================

__global__ __launch_bounds__(1024) void zeroi_k(int* __restrict__ p) {
    p[blockIdx.x * 1024 + threadIdx.x] = 0;
}

__global__ __launch_bounds__(1024) void hist2_k(const float* __restrict__ v,
                                                int* __restrict__ hist) {
    __shared__ int lh[NBINS];
    int s = blockIdx.x, b = blockIdx.y, tid = threadIdx.x;
    for (int i = tid; i < NBINS; i += 1024) lh[i] = 0;
    __syncthreads();
    const float* p = v + (size_t)b * NPIX + (size_t)s * (NPIX / HSUB);
    for (int i = tid; i < NPIX / HSUB; i += 1024) {
        int bin = (int)(p[i] * (NBINS * 0.5f));
        bin = min(max(bin, 0), NBINS - 1);
        atomicAdd(&lh[bin], 1);
    }
    __syncthreads();
    for (int i = tid; i < NBINS; i += 1024) {
        int c = lh[i];
        if (c) atomicAdd(&hist[b * NBINS + i], c);
    }
}

__global__ __launch_bounds__(1024) void gradhisth_k(const __half* __restrict__ nh,
                                                    int* __restrict__ hist) {
    __shared__ int lh[NBINS];
    int s = blockIdx.x, b = blockIdx.y, tid = threadIdx.x;
    for (int i = tid; i < NBINS; i += 1024) lh[i] = 0;
    __syncthreads();
    const __half* p = nh + (size_t)b * NPIX;
    int base = s * (NPIX / HSUB);
    for (int ii = tid; ii < NPIX / HSUB; ii += 1024) {
        int i = base + ii;
        float c = __half2float(p[i]);
        int x = i & 511, y = i >> 9;
        float dx = (x < 511) ? __half2float(p[i + 1])   - c : 0.f;
        float dy = (y < 511) ? __half2float(p[i + 512]) - c : 0.f;
        float gm = sqrtf(dx * dx + dy * dy + EPSC);
        int bin = (int)(gm * (NBINS * 0.5f));
        bin = min(max(bin, 0), NBINS - 1);
        atomicAdd(&lh[bin], 1);
    }
    __syncthreads();
    for (int i = tid; i < NBINS; i += 1024) {
        int c = lh[i];
        if (c) atomicAdd(&hist[b * NBINS + i], c);
    }
}

__global__ __launch_bounds__(1024) void quant2_k(const int* __restrict__ hist,
                                                 float* __restrict__ scal,
                                                 float q0, float q1, int s0, int s1) {
    __shared__ int csum[1025];
    __shared__ int wsum[16];
    int b = blockIdx.x, tid = threadIdx.x;
    const int* h = hist + b * NBINS;
    int s = 0;
#pragma unroll
    for (int j = 0; j < NBINS / 1024; ++j) s += h[tid * (NBINS / 1024) + j];

    int lane = tid & 63, wave = tid >> 6;
    int v = s;
#pragma unroll
    for (int off = 1; off < 64; off <<= 1) {
        int n = __shfl_up(v, off, 64);
        if (lane >= off) v += n;
    }
    if (lane == 63) wsum[wave] = v;
    __syncthreads();
    if (wave == 0 && lane < 16) {
        int w = wsum[lane];
#pragma unroll
        for (int off = 1; off < 16; off <<= 1) {
            int n = __shfl_up(w, off, 64);
            if (lane >= off) w += n;
        }
        wsum[lane] = w;
    }
    __syncthreads();
    int incl = v + (wave > 0 ? wsum[wave - 1] : 0);
    csum[tid + 1] = incl;
    if (tid == 0) csum[0] = 0;
    __syncthreads();

#pragma unroll
    for (int pass = 0; pass < 2; ++pass) {
        int slot = pass ? s1 : s0;
        if (slot < 0) continue;
        float q = pass ? q1 : q0;
        float t = q * (float)(NPIX - 1);
        if ((float)csum[tid] <= t && (float)csum[tid + 1] > t) {
            const int per = NBINS / 1024;
            int cb = csum[tid];
            int bin = tid * per;
            int hv = 1;
            for (int j = 0; j < per; ++j) {
                hv = h[tid * per + j];
                if ((float)(cb + hv) > t) { bin = tid * per + j; break; }
                cb += hv;
            }
            float k = t - (float)cb;
            scal[b * 4 + slot] = ((float)bin + (k + 0.5f) / (float)hv) * (2.0f / NBINS);
        }
    }
}

// ---------------- N_hat (fp16) from xb (fp32) ----------------
__global__ __launch_bounds__(256) void nhat2h_k(const float* __restrict__ xb,
                                                const float* __restrict__ scal,
                                                __half* __restrict__ nhh) {
    size_t i = ((size_t)blockIdx.x * 256 + threadIdx.x) * 4;
    int b = (int)(i >> 18);
    float lo = scal[b * 4 + 0], hi = scal[b * 4 + 1];
    float inv = 1.0f / (hi - lo + EPSC);
    float4 v = *(const float4*)(xb + i);
    float a0 = fminf(fmaxf((v.x - lo) * inv, 0.f), 1.f);
    float a1 = fminf(fmaxf((v.y - lo) * inv, 0.f), 1.f);
    float a2 = fminf(fmaxf((v.z - lo) * inv, 0.f), 1.f);
    float a3 = fminf(fmaxf((v.w - lo) * inv, 0.f), 1.f);
    *(__half2*)(nhh + i)     = __floats2half2_rn(a0, a1);
    *(__half2*)(nhh + i + 2) = __floats2half2_rn(a2, a3);
}

// ---------------- fused PD iteration: 8 px x RSTRIP rows per thread ----------------
__global__ __launch_bounds__(256) void pdfh5_k(const __half* __restrict__ u,
                                               const __half* __restrict__ up,
                                               const __half* __restrict__ pxO,
                                               const __half* __restrict__ pyO,
                                               __half* __restrict__ pxN,
                                               __half* __restrict__ pyN,
                                               const __half* __restrict__ nh,
                                               const float* __restrict__ scal,
                                               __half* __restrict__ un,
                                               float* __restrict__ outF,
                                               int last) {
    int x0 = threadIdx.x * 8;                          // 64 threads cover 512
    int strip = blockIdx.y * 4 + threadIdx.y;          // 0..127
    int y0 = strip * RSTRIP;
    int b = blockIdx.z;
    size_t rowbase = (size_t)b * NPIX + (size_t)y0 * 512 + x0;
    bool hasL = (x0 > 0), hasR = (x0 < 504);
    float sgm = fmaxf(scal[b * 4 + 2], EPSC);
    float inv = 1.0f / sgm;

    // center row y0
    float u_cur[8], t0[8], nh_cur[8], ubar_cur[8];
    ld8h(u + rowbase, u_cur); ld8h(up + rowbase, t0); ld8h(nh + rowbase, nh_cur);
#pragma unroll
    for (int i = 0; i < 8; ++i) ubar_cur[i] = 2.f * u_cur[i] - t0[i];

    // py_prev = py_new at row y0-1 (bit-identical halo recompute), 0 if y0==0
    float py_prev[8] = {0,0,0,0,0,0,0,0};
    if (y0 > 0) {
        float uh[8], uph[8], nhm[8], pyh[8];
        ld8h(u + rowbase - 512, uh); ld8h(up + rowbase - 512, uph);
        ld8h(nh + rowbase - 512, nhm); ld8h(pyO + rowbase - 512, pyh);
#pragma unroll
        for (int i = 0; i < 8; ++i) {
            float ubh = 2.f * uh[i] - uph[i];
            float by = bnd(nh_cur[i] - nhm[i], inv);
            py_prev[i] = __half2float(__float2half_rn(clmp(pyh[i] + SIG * (ubar_cur[i] - ubh), by)));
        }
    }

    for (int r = 0; r < RSTRIP; ++r) {
        int yr = y0 + r;
        size_t base = rowbase + (size_t)r * 512;
        bool hasD = (yr < 511);

        float ubar_nxt[8] = {0,0,0,0,0,0,0,0}, nh_nxt[8] = {0,0,0,0,0,0,0,0}, u_nxt[8] = {0,0,0,0,0,0,0,0};
        if (hasD) {
            float t1[8];
            ld8h(u + base + 512, u_nxt); ld8h(up + base + 512, t1); ld8h(nh + base + 512, nh_nxt);
#pragma unroll
            for (int i = 0; i < 8; ++i) ubar_nxt[i] = 2.f * u_nxt[i] - t1[i];
        }

        float bl = 0.f, br = 0.f, nhL = 0.f, nhR = 0.f;
        if (hasL) {
            bl = 2.f * __half2float(u[base - 1]) - __half2float(up[base - 1]);
            nhL = __half2float(nh[base - 1]);
        }
        if (hasR) {
            br = 2.f * __half2float(u[base + 8]) - __half2float(up[base + 8]);
            nhR = __half2float(nh[base + 8]);
        }

        float pxc[8], pyc[8];
        ld8h(pxO + base, pxc); ld8h(pyO + base, pyc);

        float pxm1 = 0.f;
        if (hasL) {
            float pxl = __half2float(pxO[base - 1]);
            float bxl = bnd(nh_cur[0] - nhL, inv);
            pxm1 = __half2float(__float2half_rn(clmp(pxl + SIG * (ubar_cur[0] - bl), bxl)));
        }

        float pxn[8], pyn[8];
        __half hx[8], hy[8];
#pragma unroll
        for (int i = 0; i < 8; ++i) {
            float nright = (i < 7) ? nh_cur[i + 1] : nhR;
            float dxn = (x0 + i < 511) ? (nright - nh_cur[i]) : 0.f;
            float bxc = bnd(dxn, inv);
            float byc = bnd(hasD ? (nh_nxt[i] - nh_cur[i]) : 0.f, inv);

            float right = (i < 7) ? ubar_cur[i + 1] : br;
            float dx = (x0 + i < 511) ? right - ubar_cur[i] : 0.f;
            __half h = __float2half_rn(clmp(pxc[i] + SIG * dx, bxc));
            hx[i] = h; pxn[i] = __half2float(h);
            float dy = hasD ? ubar_nxt[i] - ubar_cur[i] : 0.f;
            __half h2 = __float2half_rn(clmp(pyc[i] + SIG * dy, byc));
            hy[i] = h2; pyn[i] = __half2float(h2);
        }

        if (!last) {
            float4 vx, vy;
            __half2* px2 = (__half2*)&vx; __half2* py2 = (__half2*)&vy;
#pragma unroll
            for (int j = 0; j < 4; ++j) {
                px2[j] = __half2(hx[2 * j], hx[2 * j + 1]);
                py2[j] = __half2(hy[2 * j], hy[2 * j + 1]);
            }
            *(float4*)(pxN + base) = vx;
            *(float4*)(pyN + base) = vy;
        }

        float unew[8];
#pragma unroll
        for (int i = 0; i < 8; ++i) {
            float left = (i > 0) ? pxn[i - 1] : pxm1;
            float div = pxn[i] + pyn[i] - left - py_prev[i];
            unew[i] = (u_cur[i] + TAUC * div + TAUC * nh_cur[i]) * (1.0f / (1.0f + TAUC));
        }
        if (last) {
            float4 o0, o1;
            o0.x = fminf(fmaxf(unew[0], 0.f), 1.f);
            o0.y = fminf(fmaxf(unew[1], 0.f), 1.f);
            o0.z = fminf(fmaxf(unew[2], 0.f), 1.f);
            o0.w = fminf(fmaxf(unew[3], 0.f), 1.f);
            o1.x = fminf(fmaxf(unew[4], 0.f), 1.f);
            o1.y = fminf(fmaxf(unew[5], 0.f), 1.f);
            o1.z = fminf(fmaxf(unew[6], 0.f), 1.f);
            o1.w = fminf(fmaxf(unew[7], 0.f), 1.f);
            *(float4*)(outF + base)     = o0;
            *(float4*)(outF + base + 4) = o1;
        } else {
            float4 vu;
            __half2* hu = (__half2*)&vu;
#pragma unroll
            for (int j = 0; j < 4; ++j) hu[j] = __floats2half2_rn(unew[2 * j], unew[2 * j + 1]);
            *(float4*)(un + base) = vu;
        }

        // rotate rows
#pragma unroll
        for (int i = 0; i < 8; ++i) {
            u_cur[i] = u_nxt[i];
            ubar_cur[i] = ubar_nxt[i];
            nh_cur[i] = nh_nxt[i];
            py_prev[i] = pyn[i];
        }
    }
}

extern "C" void kernel_launch(void* const* d_in, const int* in_sizes, int n_in,
                              void* d_out, int out_size, void* d_ws, size_t ws_size,
                              hipStream_t stream) {
    const float* Iy = (const float*)d_in[0];
    float* ws = (float*)d_ws;
    float* out = (float*)d_out;

    dim3 hist_g(HSUB, 16);
    dim3 pd_b(64, 4), pd_g(1, 512 / RSTRIP / 4, 16);

    float*  xb = ws;
    float*  H  = ws + (size_t)NP;
    __half* hb = (__half*)(ws + (size_t)3 * NP);
    __half* nhh = hb;
    __half* HA  = hb + (size_t)NP;
    __half* HB  = hb + (size_t)2 * NP;
    __half* HC  = hb + (size_t)3 * NP;
    __half* pxA = hb + (size_t)4 * NP;
    __half* pyA = hb + (size_t)5 * NP;
    __half* pxB = hb + (size_t)6 * NP;
    __half* pyB = hb + (size_t)7 * NP;
    int*    hist = (int*)(ws + (size_t)7 * NP);
    float*  scal = ws + (size_t)7 * NP + 16 * NBINS;

    // 1. separable 31x31 max pool (R and M=max(G,B)) fused with Dmip combine
    hpass3_k<<<dim3(64, 32), dim3(512), 0, stream>>>(Iy, H);
    vpassC_k<<<dim3(8, 9, 16), dim3(64), 0, stream>>>(H, Iy, xb);

    // 2. robust normalize -> fp16 N_hat
    zeroi_k<<<16 * NBINS / 1024, 1024, 0, stream>>>(hist);
    hist2_k<<<hist_g, 1024, 0, stream>>>(xb, hist);
    quant2_k<<<16, 1024, 0, stream>>>(hist, scal, 0.01f, 0.99f, 0, 1);
    nhat2h_k<<<NP / 1024, 256, 0, stream>>>(xb, scal, nhh);

    // 3. sigma (median grad mag); zero fp16 p (pxA,pyA contiguous)
    zeroi_k<<<16 * NBINS / 1024, 1024, 0, stream>>>(hist);
    gradhisth_k<<<hist_g, 1024, 0, stream>>>(nhh, hist);
    quant2_k<<<16, 1024, 0, stream>>>(hist, scal, 0.5f, 0.5f, 2, -1);
    hipMemsetAsync(pxA, 0, (size_t)2 * NP * sizeof(__half), stream);

    // 4. 30 fused PD iterations (u_bar = 2u - u_prev), fp16 state, y-strip
    const __half* ucur = nhh;
    const __half* uprev = nhh;
    __half* Ubuf[3] = {HA, HB, HC};
    __half* pxs[2] = {pxA, pxB};
    __half* pys[2] = {pyA, pyB};
    for (int t = 0; t < 30; ++t) {
        __half* un = Ubuf[t % 3];
        int cur = t & 1;
        pdfh5_k<<<pd_g, pd_b, 0, stream>>>(ucur, uprev,
                                           pxs[cur], pys[cur],
                                           pxs[cur ^ 1], pys[cur ^ 1],
                                           nhh, scal, un, out, (t == 29) ? 1 : 0);
        uprev = ucur;
        ucur = un;
    }
    // t=29 wrote clipped fp32 result directly to out.
}

// Round 8
// 490.354 us; speedup vs baseline: 3.4773x; 1.1890x over previous
//
#include <hip/hip_runtime.h>
#include <hip/hip_bf16.h>
#include <hip/hip_fp16.h>
#include <math.h>

#define NPIX   262144          // 512*512
#define NP     4194304         // 16*512*512
#define NBINS  8192
#define HSUB   16
#define RB     8               // output rows per block in fused PD kernel
#define SIG    0.125f
#define TAUC   0.125f
#define ALPHAC 0.15f
#define MUC    10.0f
#define EPSC   1e-6f
#define NEGINF -3.4e38f
#define IVT    (1.0f / (1.0f + TAUC))

// ---------- helpers ----------
__device__ __forceinline__ void cvt8h(float4 raw, float* d) {
    const __half2* h = (const __half2*)&raw;
#pragma unroll
    for (int j = 0; j < 4; ++j) {
        float2 f = __half22float2(h[j]);
        d[2 * j] = f.x; d[2 * j + 1] = f.y;
    }
}
__device__ __forceinline__ void ld8h(const __half* p, float* d) {
    cvt8h(*(const float4*)p, d);
}
__device__ __forceinline__ void ld8f(const float* p, float* d) {
    float4 t0 = *(const float4*)p;
    float4 t1 = *(const float4*)(p + 4);
    d[0]=t0.x; d[1]=t0.y; d[2]=t0.z; d[3]=t0.w;
    d[4]=t1.x; d[5]=t1.y; d[6]=t1.z; d[7]=t1.w;
}
__device__ __forceinline__ float4 pk8h(const float* s) {
    float4 r; __half2* h = (__half2*)&r;
#pragma unroll
    for (int j = 0; j < 4; ++j) h[j] = __floats2half2_rn(s[2 * j], s[2 * j + 1]);
    return r;
}
__device__ __forceinline__ float bnd(float d, float inv) {
    return ALPHAC * (1.f + MUC * __expf(-fabsf(d) * inv));
}
__device__ __forceinline__ float clmp(float v, float b) {
    return fminf(fmaxf(v, -b), b);
}

// ================= POOLING =================

__global__ __launch_bounds__(512) void hpass3_k(const float* __restrict__ Iy,
                                                float* __restrict__ H) {
    __shared__ float rowbuf[8][512];
    __shared__ float PB[8][512];
    __shared__ float SB[8][512];
    int tid = threadIdx.x;
    int plane = blockIdx.y;
    int y0 = blockIdx.x * 8;

#pragma unroll
    for (int q = 0; q < 2; ++q) {
        int idx = q * 512 + tid;
        int r = idx >> 7;
        int x4 = (idx & 127) << 2;
        float4 v;
        if (plane < 16) {
            v = *(const float4*)(Iy + (size_t)(plane * 3) * NPIX + (size_t)(y0 + r) * 512 + x4);
        } else {
            int b = plane - 16;
            float4 g = *(const float4*)(Iy + ((size_t)(b * 3) + 1) * NPIX + (size_t)(y0 + r) * 512 + x4);
            float4 bb = *(const float4*)(Iy + ((size_t)(b * 3) + 2) * NPIX + (size_t)(y0 + r) * 512 + x4);
            v = make_float4(fmaxf(g.x, bb.x), fmaxf(g.y, bb.y), fmaxf(g.z, bb.z), fmaxf(g.w, bb.w));
        }
        *(float4*)(&rowbuf[r][x4]) = v;
    }
    __syncthreads();

    if (tid < 272) {
        int type = tid / 136;
        int rem = tid % 136;
        int r = rem / 17;
        int seg = rem % 17;
        int s0 = seg * 31;
        if (type == 0) {
            float run = rowbuf[r][s0];
            PB[r][s0] = run;
            for (int j = 1; j < 31; ++j) {
                int idx = s0 + j;
                if (idx < 512) { run = fmaxf(run, rowbuf[r][idx]); PB[r][idx] = run; }
            }
        } else {
            int s1 = min(s0 + 30, 511);
            float run = rowbuf[r][s1];
            SB[r][s1] = run;
            for (int j = s1 - 1; j >= s0; --j) { run = fmaxf(run, rowbuf[r][j]); SB[r][j] = run; }
        }
    }
    __syncthreads();

    int x = tid, a = x - 15, bc = x + 15;
#pragma unroll
    for (int r = 0; r < 8; ++r) {
        float o;
        if (a < 0)        o = PB[r][bc];
        else if (bc > 511) o = fmaxf(SB[r][a], PB[r][511]);
        else              o = fmaxf(SB[r][a], PB[r][bc]);
        H[(size_t)plane * NPIX + (size_t)(y0 + r) * 512 + x] = o;
    }
}

__global__ __launch_bounds__(64) void vpassC_k(const float* __restrict__ H,
                                               const float* __restrict__ Iy,
                                               float* __restrict__ xb) {
    int x = blockIdx.x * 64 + threadIdx.x;
    int b = blockIdx.z;
    const float* inR = H + (size_t)b * NPIX;
    const float* inM = H + (size_t)(16 + b) * NPIX;
    const float* IyR = Iy + (size_t)(b * 3) * NPIX;
    float*       out = xb + (size_t)b * NPIX;
    int c0 = blockIdx.y * 2;

    float SprevR[31], SprevM[31];
    if (c0 > 0) {
        int s0 = (c0 - 1) * 31;
        float vR[31], vM[31];
#pragma unroll
        for (int j = 0; j < 31; ++j) {
            vR[j] = inR[(size_t)(s0 + j) * 512 + x];
            vM[j] = inM[(size_t)(s0 + j) * 512 + x];
        }
        float aR = NEGINF, aM = NEGINF;
#pragma unroll
        for (int j = 30; j >= 0; --j) {
            aR = fmaxf(aR, vR[j]); SprevR[j] = aR;
            aM = fmaxf(aM, vM[j]); SprevM[j] = aM;
        }
    } else {
#pragma unroll
        for (int j = 0; j < 31; ++j) { SprevR[j] = NEGINF; SprevM[j] = NEGINF; }
    }

    int send = min(c0 + 1, 16);
    for (int s = c0; s <= send; ++s) {
        int s0 = s * 31;
        float vR[31], vM[31];
#pragma unroll
        for (int j = 0; j < 31; ++j) {
            bool ok = (s0 + j < 512);
            vR[j] = ok ? inR[(size_t)(s0 + j) * 512 + x] : NEGINF;
            vM[j] = ok ? inM[(size_t)(s0 + j) * 512 + x] : NEGINF;
        }
        float ScurR[31], ScurM[31];
        float aR = NEGINF, aM = NEGINF;
#pragma unroll
        for (int j = 30; j >= 0; --j) {
            aR = fmaxf(aR, vR[j]); ScurR[j] = aR;
            aM = fmaxf(aM, vM[j]); ScurM[j] = aM;
        }
        float PR = NEGINF, PM = NEGINF;
#pragma unroll
        for (int r = 0; r < 31; ++r) {
            PR = fmaxf(PR, vR[r]);
            PM = fmaxf(PM, vM[r]);
            int i = s0 + r - 15;
            if (i >= 0 && i <= 511) {
                int a = s0 - 30 + r;
                float oR, oM;
                if (a < 0) { oR = PR; oM = PM; }
                else {
                    float SvR = (r == 30) ? ScurR[0] : SprevR[r + 1];
                    float SvM = (r == 30) ? ScurM[0] : SprevM[r + 1];
                    oR = fmaxf(SvR, PR);
                    oM = fmaxf(SvM, PM);
                }
                out[(size_t)i * 512 + x] = fabsf(oR - oM) + IyR[(size_t)i * 512 + x];
            }
        }
#pragma unroll
        for (int j = 0; j < 31; ++j) { SprevR[j] = ScurR[j]; SprevM[j] = ScurM[j]; }
    }
}

// ================= HISTOGRAM / QUANTILE =================

__global__ __launch_bounds__(1024) void zeroi_k(int* __restrict__ p) {
    p[blockIdx.x * 1024 + threadIdx.x] = 0;
}

__global__ __launch_bounds__(1024) void hist2_k(const float* __restrict__ v,
                                                int* __restrict__ hist) {
    __shared__ int lh[NBINS];
    int s = blockIdx.x, b = blockIdx.y, tid = threadIdx.x;
    for (int i = tid; i < NBINS; i += 1024) lh[i] = 0;
    __syncthreads();
    const float* p = v + (size_t)b * NPIX + (size_t)s * (NPIX / HSUB);
    for (int i = tid; i < NPIX / HSUB; i += 1024) {
        int bin = (int)(p[i] * (NBINS * 0.5f));
        bin = min(max(bin, 0), NBINS - 1);
        atomicAdd(&lh[bin], 1);
    }
    __syncthreads();
    for (int i = tid; i < NBINS; i += 1024) {
        int c = lh[i];
        if (c) atomicAdd(&hist[b * NBINS + i], c);
    }
}

__global__ __launch_bounds__(1024) void gradhisth_k(const __half* __restrict__ nh,
                                                    int* __restrict__ hist) {
    __shared__ int lh[NBINS];
    int s = blockIdx.x, b = blockIdx.y, tid = threadIdx.x;
    for (int i = tid; i < NBINS; i += 1024) lh[i] = 0;
    __syncthreads();
    const __half* p = nh + (size_t)b * NPIX;
    int base = s * (NPIX / HSUB);
    for (int ii = tid; ii < NPIX / HSUB; ii += 1024) {
        int i = base + ii;
        float c = __half2float(p[i]);
        int x = i & 511, y = i >> 9;
        float dx = (x < 511) ? __half2float(p[i + 1])   - c : 0.f;
        float dy = (y < 511) ? __half2float(p[i + 512]) - c : 0.f;
        float gm = sqrtf(dx * dx + dy * dy + EPSC);
        int bin = (int)(gm * (NBINS * 0.5f));
        bin = min(max(bin, 0), NBINS - 1);
        atomicAdd(&lh[bin], 1);
    }
    __syncthreads();
    for (int i = tid; i < NBINS; i += 1024) {
        int c = lh[i];
        if (c) atomicAdd(&hist[b * NBINS + i], c);
    }
}

__global__ __launch_bounds__(1024) void quant2_k(const int* __restrict__ hist,
                                                 float* __restrict__ scal,
                                                 float q0, float q1, int s0, int s1) {
    __shared__ int csum[1025];
    __shared__ int wsum[16];
    int b = blockIdx.x, tid = threadIdx.x;
    const int* h = hist + b * NBINS;
    int s = 0;
#pragma unroll
    for (int j = 0; j < NBINS / 1024; ++j) s += h[tid * (NBINS / 1024) + j];

    int lane = tid & 63, wave = tid >> 6;
    int v = s;
#pragma unroll
    for (int off = 1; off < 64; off <<= 1) {
        int n = __shfl_up(v, off, 64);
        if (lane >= off) v += n;
    }
    if (lane == 63) wsum[wave] = v;
    __syncthreads();
    if (wave == 0 && lane < 16) {
        int w = wsum[lane];
#pragma unroll
        for (int off = 1; off < 16; off <<= 1) {
            int n = __shfl_up(w, off, 64);
            if (lane >= off) w += n;
        }
        wsum[lane] = w;
    }
    __syncthreads();
    int incl = v + (wave > 0 ? wsum[wave - 1] : 0);
    csum[tid + 1] = incl;
    if (tid == 0) csum[0] = 0;
    __syncthreads();

#pragma unroll
    for (int pass = 0; pass < 2; ++pass) {
        int slot = pass ? s1 : s0;
        if (slot < 0) continue;
        float q = pass ? q1 : q0;
        float t = q * (float)(NPIX - 1);
        if ((float)csum[tid] <= t && (float)csum[tid + 1] > t) {
            const int per = NBINS / 1024;
            int cb = csum[tid];
            int bin = tid * per;
            int hv = 1;
            for (int j = 0; j < per; ++j) {
                hv = h[tid * per + j];
                if ((float)(cb + hv) > t) { bin = tid * per + j; break; }
                cb += hv;
            }
            float k = t - (float)cb;
            scal[b * 4 + slot] = ((float)bin + (k + 0.5f) / (float)hv) * (2.0f / NBINS);
        }
    }
}

// ---------------- N_hat (fp16) from xb (fp32) ----------------
__global__ __launch_bounds__(256) void nhat2h_k(const float* __restrict__ xb,
                                                const float* __restrict__ scal,
                                                __half* __restrict__ nhh) {
    size_t i = ((size_t)blockIdx.x * 256 + threadIdx.x) * 4;
    int b = (int)(i >> 18);
    float lo = scal[b * 4 + 0], hi = scal[b * 4 + 1];
    float inv = 1.0f / (hi - lo + EPSC);
    float4 v = *(const float4*)(xb + i);
    float a0 = fminf(fmaxf((v.x - lo) * inv, 0.f), 1.f);
    float a1 = fminf(fmaxf((v.y - lo) * inv, 0.f), 1.f);
    float a2 = fminf(fmaxf((v.z - lo) * inv, 0.f), 1.f);
    float a3 = fminf(fmaxf((v.w - lo) * inv, 0.f), 1.f);
    *(__half2*)(nhh + i)     = __floats2half2_rn(a0, a1);
    *(__half2*)(nhh + i + 2) = __floats2half2_rn(a2, a3);
}

// ================= FUSED 2-ITERATION PD KERNEL =================
// Per block: 8 output rows x 512 px x 1 batch. 5 LDS phases.
// All intermediates (p^{t+1}, u^{t+1}, p^{t+2}) fp16-rounded at creation ->
// bit-identical across blocks recomputing the same halo row.
__global__ __launch_bounds__(256) void pdf2_k(const __half* __restrict__ u,
                                              const __half* __restrict__ up,
                                              const __half* __restrict__ pxO,
                                              const __half* __restrict__ pyO,
                                              __half* __restrict__ pxN,
                                              __half* __restrict__ pyN,
                                              const __half* __restrict__ nh,
                                              const float* __restrict__ scal,
                                              __half* __restrict__ u1g,
                                              __half* __restrict__ u2g,
                                              float* __restrict__ outF,
                                              int last) {
    __shared__ __align__(16) char smem[75776];            // 74 KB
    float  (*ubar0)[512] = (float (*)[512])smem;          // 12 rows fp32 (ph 0-A), 24 KB
    __half (*u1l)[512]   = (__half(*)[512])smem;          // 10 rows (ph B+), reuses ubar0
    __half (*u0l)[512]   = (__half(*)[512])(smem + 10240);// 10 rows (ph B+)
    __half (*nhl)[512]   = (__half(*)[512])(smem + 24576);// 12 rows
    __half (*px1)[512]   = (__half(*)[512])(smem + 36864);// 10 rows (rows y0-1..y0+8)
    __half (*py1)[512]   = (__half(*)[512])(smem + 47104);// 11 rows (rows y0-2..y0+8)
    __half (*px2l)[512]  = (__half(*)[512])(smem + 58368);// 8 rows  (rows y0..y0+7)
    __half (*py2l)[512]  = (__half(*)[512])(smem + 66560);// 9 rows  (rows y0-1..y0+7)

    int tid = threadIdx.x;
    int sub = tid >> 6, lane = tid & 63, x0 = lane * 8;
    int y0 = blockIdx.x * RB;
    int b = blockIdx.y;
    size_t plane = (size_t)b * NPIX;
    float sgm = fmaxf(scal[b * 4 + 2], EPSC);
    float inv = 1.0f / sgm;
    const float4 z4 = make_float4(0.f, 0.f, 0.f, 0.f);

    // ---- Phase 0: ubar^t (fp32) + nh rows y0-2..y0+9 ----
    for (int i = sub; i < 12; i += 4) {
        int g = y0 - 2 + i;
        if (g >= 0 && g < 512) {
            size_t off = plane + (size_t)g * 512 + x0;
            float uu[8], pp[8];
            ld8h(u + off, uu); ld8h(up + off, pp);
#pragma unroll
            for (int j = 0; j < 8; ++j) ubar0[i][x0 + j] = 2.f * uu[j] - pp[j];
            *(float4*)&nhl[i][x0] = *(const float4*)(nh + off);
        } else {
            *(float4*)&ubar0[i][x0]     = z4;
            *(float4*)&ubar0[i][x0 + 4] = z4;
            *(float4*)&nhl[i][x0] = z4;
        }
    }
    __syncthreads();

    // ---- Phase A: p^{t+1}: py1 rows y0-2..y0+8 (c=0..10), px1 rows y0-1..y0+8 (c>=1) ----
    for (int c = sub; c < 11; c += 4) {
        int g = y0 - 2 + c;
        if (g >= 0 && g < 512) {
            size_t off = plane + (size_t)g * 512 + x0;
            float nhc[8], nhd[8], ubc[8], ubd[8];
            ld8h(&nhl[c][x0], nhc);
            ld8h(&nhl[c + 1][x0], nhd);
            ld8f(&ubar0[c][x0], ubc);
            ld8f(&ubar0[c + 1][x0], ubd);
            float nhRr = (lane < 63) ? __half2float(nhl[c][x0 + 8]) : 0.f;
            float ubRr = (lane < 63) ? ubar0[c][x0 + 8] : 0.f;
            bool rD = (g < 511);
            float py0v[8]; ld8h(pyO + off, py0v);
            float pyv[8];
#pragma unroll
            for (int j = 0; j < 8; ++j) {
                float by = bnd(rD ? (nhd[j] - nhc[j]) : 0.f, inv);
                float dy = rD ? (ubd[j] - ubc[j]) : 0.f;
                pyv[j] = clmp(py0v[j] + SIG * dy, by);
            }
            *(float4*)&py1[c][x0] = pk8h(pyv);
            if (c >= 1) {
                float px0v[8]; ld8h(pxO + off, px0v);
                float pxv[8];
#pragma unroll
                for (int j = 0; j < 8; ++j) {
                    int x = x0 + j;
                    bool xok = (x < 511);
                    float nhr = (j < 7) ? nhc[j + 1] : nhRr;
                    float ubr = (j < 7) ? ubc[j + 1] : ubRr;
                    float bx = bnd(xok ? (nhr - nhc[j]) : 0.f, inv);
                    float dx = xok ? (ubr - ubc[j]) : 0.f;
                    pxv[j] = clmp(px0v[j] + SIG * dx, bx);
                }
                *(float4*)&px1[c - 1][x0] = pk8h(pxv);
            }
        } else {
            *(float4*)&py1[c][x0] = z4;
            if (c >= 1) *(float4*)&px1[c - 1][x0] = z4;
        }
    }
    __syncthreads();

    // ---- Phase B: u^{t+1} rows y0-1..y0+8 (a=0..9); write interior to u1g ----
    for (int a = sub; a < 10; a += 4) {
        int g = y0 - 1 + a;
        if (g >= 0 && g < 512) {
            size_t off = plane + (size_t)g * 512 + x0;
            float4 u0raw = *(const float4*)(u + off);
            float u0v[8]; cvt8h(u0raw, u0v);
            float nhc[8];  ld8h(&nhl[a + 1][x0], nhc);
            float px1c[8]; ld8h(&px1[a][x0], px1c);
            float py1c[8]; ld8h(&py1[a + 1][x0], py1c);
            float py1u[8]; ld8h(&py1[a][x0], py1u);
            float pxl = (x0 > 0) ? __half2float(px1[a][x0 - 1]) : 0.f;
            bool gU = (g > 0);
            float uv[8];
#pragma unroll
            for (int j = 0; j < 8; ++j) {
                int x = x0 + j;
                float left = (x > 0) ? ((j > 0) ? px1c[j - 1] : pxl) : 0.f;
                float div = px1c[j] - left + py1c[j] - (gU ? py1u[j] : 0.f);
                uv[j] = (u0v[j] + TAUC * div + TAUC * nhc[j]) * IVT;
            }
            float4 packed = pk8h(uv);
            *(float4*)&u1l[a][x0] = packed;
            *(float4*)&u0l[a][x0] = u0raw;
            if (g >= y0 && g < y0 + RB) *(float4*)(u1g + off) = packed;
        } else {
            *(float4*)&u1l[a][x0] = z4;
            *(float4*)&u0l[a][x0] = z4;
        }
    }
    __syncthreads();

    // ---- Phase C: p^{t+2}: py2 rows y0-1..y0+7 (e=0..8), px2 rows y0..y0+7 (e>=1) ----
    for (int e = sub; e < 9; e += 4) {
        int g = y0 - 1 + e;
        if (g >= 0) {                      // g <= 511 always here
            size_t off = plane + (size_t)g * 512 + x0;
            float u1c[8], u0c[8], u1d[8], u0d[8];
            ld8h(&u1l[e][x0], u1c);     ld8h(&u0l[e][x0], u0c);
            ld8h(&u1l[e + 1][x0], u1d); ld8h(&u0l[e + 1][x0], u0d);
            float nhc[8], nhd[8];
            ld8h(&nhl[e + 1][x0], nhc); ld8h(&nhl[e + 2][x0], nhd);
            float ubc[8], ubd[8];
#pragma unroll
            for (int j = 0; j < 8; ++j) {
                ubc[j] = 2.f * u1c[j] - u0c[j];
                ubd[j] = 2.f * u1d[j] - u0d[j];
            }
            float ubRr = (lane < 63) ? (2.f * __half2float(u1l[e][x0 + 8]) - __half2float(u0l[e][x0 + 8])) : 0.f;
            float nhRr = (lane < 63) ? __half2float(nhl[e + 1][x0 + 8]) : 0.f;
            bool rD = (g < 511);
            float py1c[8]; ld8h(&py1[e + 1][x0], py1c);
            float pyv[8];
#pragma unroll
            for (int j = 0; j < 8; ++j) {
                float by = bnd(rD ? (nhd[j] - nhc[j]) : 0.f, inv);
                float dy = rD ? (ubd[j] - ubc[j]) : 0.f;
                pyv[j] = clmp(py1c[j] + SIG * dy, by);
            }
            float4 pyp = pk8h(pyv);
            *(float4*)&py2l[e][x0] = pyp;
            if (g >= y0) *(float4*)(pyN + off) = pyp;
            if (e >= 1) {
                float px1c[8]; ld8h(&px1[e][x0], px1c);
                float pxv[8];
#pragma unroll
                for (int j = 0; j < 8; ++j) {
                    int x = x0 + j;
                    bool xok = (x < 511);
                    float nhr = (j < 7) ? nhc[j + 1] : nhRr;
                    float ubr = (j < 7) ? ubc[j + 1] : ubRr;
                    float bx = bnd(xok ? (nhr - nhc[j]) : 0.f, inv);
                    float dx = xok ? (ubr - ubc[j]) : 0.f;
                    pxv[j] = clmp(px1c[j] + SIG * dx, bx);
                }
                float4 pxp = pk8h(pxv);
                *(float4*)&px2l[e - 1][x0] = pxp;
                *(float4*)(pxN + off) = pxp;
            }
        } else {
            *(float4*)&py2l[e][x0] = z4;
        }
    }
    __syncthreads();

    // ---- Phase D: u^{t+2} rows y0..y0+7 ----
    for (int d = sub; d < 8; d += 4) {
        int g = y0 + d;
        size_t off = plane + (size_t)g * 512 + x0;
        float px2c[8]; ld8h(&px2l[d][x0], px2c);
        float py2c[8]; ld8h(&py2l[d + 1][x0], py2c);
        float py2u[8]; ld8h(&py2l[d][x0], py2u);
        float pxl = (x0 > 0) ? __half2float(px2l[d][x0 - 1]) : 0.f;
        float u1c[8]; ld8h(&u1l[d + 1][x0], u1c);
        float nhc[8]; ld8h(&nhl[d + 2][x0], nhc);
        bool gU = (g > 0);
        float uv[8];
#pragma unroll
        for (int j = 0; j < 8; ++j) {
            int x = x0 + j;
            float left = (x > 0) ? ((j > 0) ? px2c[j - 1] : pxl) : 0.f;
            float div = px2c[j] - left + py2c[j] - (gU ? py2u[j] : 0.f);
            uv[j] = (u1c[j] + TAUC * div + TAUC * nhc[j]) * IVT;
        }
        if (last) {
            float4 o0, o1;
            o0.x = fminf(fmaxf(uv[0], 0.f), 1.f);
            o0.y = fminf(fmaxf(uv[1], 0.f), 1.f);
            o0.z = fminf(fmaxf(uv[2], 0.f), 1.f);
            o0.w = fminf(fmaxf(uv[3], 0.f), 1.f);
            o1.x = fminf(fmaxf(uv[4], 0.f), 1.f);
            o1.y = fminf(fmaxf(uv[5], 0.f), 1.f);
            o1.z = fminf(fmaxf(uv[6], 0.f), 1.f);
            o1.w = fminf(fmaxf(uv[7], 0.f), 1.f);
            *(float4*)(outF + off)     = o0;
            *(float4*)(outF + off + 4) = o1;
        } else {
            *(float4*)(u2g + off) = pk8h(uv);
        }
    }
}

extern "C" void kernel_launch(void* const* d_in, const int* in_sizes, int n_in,
                              void* d_out, int out_size, void* d_ws, size_t ws_size,
                              hipStream_t stream) {
    const float* Iy = (const float*)d_in[0];
    float* ws = (float*)d_ws;
    float* out = (float*)d_out;

    dim3 hist_g(HSUB, 16);
    dim3 pd2_g(512 / RB, 16);

    // layout (float units): 0..NP: xb fp32 | NP..3NP: H (2 planes fp32)
    // 3NP..7.5NP: fp16 arrays (9*NP halfs) | 7.5NP: hist, scal
    float*  xb = ws;
    float*  H  = ws + (size_t)NP;
    __half* hb = (__half*)(ws + (size_t)3 * NP);
    __half* nhh = hb;
    __half* HA  = hb + (size_t)NP;
    __half* HB  = hb + (size_t)2 * NP;
    __half* HC  = hb + (size_t)3 * NP;
    __half* HD  = hb + (size_t)4 * NP;
    __half* pxA = hb + (size_t)5 * NP;
    __half* pyA = hb + (size_t)6 * NP;
    __half* pxB = hb + (size_t)7 * NP;
    __half* pyB = hb + (size_t)8 * NP;
    int*    hist = (int*)(ws + (size_t)15 * NP / 2);
    float*  scal = ws + (size_t)15 * NP / 2 + 16 * NBINS;

    // 1. separable 31x31 max pool (R and M=max(G,B)) fused with Dmip combine
    hpass3_k<<<dim3(64, 32), dim3(512), 0, stream>>>(Iy, H);
    vpassC_k<<<dim3(8, 9, 16), dim3(64), 0, stream>>>(H, Iy, xb);

    // 2. robust normalize -> fp16 N_hat
    zeroi_k<<<16 * NBINS / 1024, 1024, 0, stream>>>(hist);
    hist2_k<<<hist_g, 1024, 0, stream>>>(xb, hist);
    quant2_k<<<16, 1024, 0, stream>>>(hist, scal, 0.01f, 0.99f, 0, 1);
    nhat2h_k<<<NP / 1024, 256, 0, stream>>>(xb, scal, nhh);

    // 3. sigma (median grad mag); zero fp16 p (pxA,pyA contiguous)
    zeroi_k<<<16 * NBINS / 1024, 1024, 0, stream>>>(hist);
    gradhisth_k<<<hist_g, 1024, 0, stream>>>(nhh, hist);
    quant2_k<<<16, 1024, 0, stream>>>(hist, scal, 0.5f, 0.5f, 2, -1);
    hipMemsetAsync(pxA, 0, (size_t)2 * NP * sizeof(__half), stream);

    // 4. 15 fused launches x 2 PD iterations (u_bar = 2u - u_prev)
    const __half* ucur = nhh;
    const __half* uprev = nhh;
    __half* pxs[2] = {pxA, pxB};
    __half* pys[2] = {pyA, pyB};
    for (int k = 0; k < 15; ++k) {
        int cur = k & 1;
        __half* u1o = (k & 1) ? HC : HA;
        __half* u2o = (k & 1) ? HD : HB;
        pdf2_k<<<pd2_g, 256, 0, stream>>>(ucur, uprev,
                                          pxs[cur], pys[cur],
                                          pxs[cur ^ 1], pys[cur ^ 1],
                                          nhh, scal, u1o, u2o, out,
                                          (k == 14) ? 1 : 0);
        uprev = u1o;
        ucur = u2o;
    }
    // k=14 wrote clipped fp32 result directly to out.
}